// Round 14
// baseline (2954.089 us; speedup 1.0000x reference)
//
#include <hip/hip_runtime.h>
#include <math.h>

typedef short s16x4 __attribute__((ext_vector_type(4)));
typedef short s16x8 __attribute__((ext_vector_type(8)));
typedef float f32x4 __attribute__((ext_vector_type(4)));
typedef unsigned short us;
typedef unsigned long long ull;

#define WAITVM(N) do { asm volatile("s_waitcnt vmcnt(" #N ")" ::: "memory"); __builtin_amdgcn_sched_barrier(0); } while (0)

namespace {
constexpr int T = 80, Fdim = 32, H = 512, OSTR = 34;

__device__ __forceinline__ us f2bf(float f) {
  union { float f; unsigned u; } x; x.f = f;
  unsigned u = x.u; u += 0x7fffu + ((u >> 16) & 1u);
  return (us)(u >> 16);
}
__device__ __forceinline__ float bf2f(us s) {
  union { unsigned u; float f; } x; x.u = ((unsigned)s) << 16; return x.f;
}
__device__ __forceinline__ float sigf(float v) { return 1.f / (1.f + expf(-v)); }
__device__ __forceinline__ float geluf(float v) {
  return 0.5f * v * (1.f + erff(v * 0.70710678118654752f));
}

__device__ __forceinline__ ull ald8(const void* p) {
  return __hip_atomic_load((const ull*)p, __ATOMIC_RELAXED, __HIP_MEMORY_SCOPE_AGENT);
}
__device__ __forceinline__ void ast8(void* p, ull v) {
  __hip_atomic_store((ull*)p, v, __ATOMIC_RELAXED, __HIP_MEMORY_SCOPE_AGENT);
}

union U8 { ull u; s16x4 v4; float f[2]; };
union S8 { s16x8 v; ull u[2]; };

struct SetA { ull a0, a1; };
struct SetB { s16x8 b10, b11, b00, b01; };
struct HSetB { s16x8 b0h, b0l, b1h, b1l; };

// ---------------- weight pre-pack (unchanged) ----------------
__global__ __launch_bounds__(256)
void pack_w_kernel(const float* __restrict__ w1, const float* __restrict__ w2,
                   int K1, int K2, int NKC, int head, us* __restrict__ dst) {
  int bid = blockIdx.x;
  int jb = bid / NKC, kc = bid % NKC;
  int tid = threadIdx.x;
  int strip = tid >> 6, l = tid & 63;
  int nl = l & 15, kg = l >> 4;
  int n = head ? (jb * 64 + strip * 16 + nl) : (strip * 512 + jb * 16 + nl);
  s16x8 h8, l8;
  #pragma unroll
  for (int i = 0; i < 8; ++i) {
    int k = kc * 32 + kg * 8 + i;
    float v = (k < K1) ? w1[(size_t)n * K1 + k] : w2[(size_t)n * K2 + (k - K1)];
    us h = f2bf(v);
    h8[i] = (short)h;
    l8[i] = (short)f2bf(v - bf2f(h));
  }
  size_t base = (size_t)bid * 4096;
  *(s16x8*)&dst[base + (size_t)(strip * 2 + 0) * 512 + l * 8] = h8;
  *(s16x8*)&dst[base + (size_t)(strip * 2 + 1) * 512 + l * 8] = l8;
}

__global__ __launch_bounds__(256)
void bsum_kernel(const float* bi0, const float* bh0, const float* bi1, const float* bh1,
                 float* bs0, float* bs1) {
  int i = blockIdx.x * 256 + threadIdx.x;
  if (i < 2048) bs0[i] = bi0[i] + bh0[i];
  else { int j = i - 2048; bs1[j] = bi1[j] + bh1[j]; }
}

// ---------------- persistent whole-model kernel ----------------
// 256 WGs of 512 threads = 8 groups (64 rows) x 32 WGs (16 h-cols).
// 8 waves/WG: waves 0-3 (pset0) even K-chunks, waves 4-7 (pset1) odd chunks.
// Same tile, accumulators merged via LDS. 2 waves/SIMD -> TLP.
__global__ __launch_bounds__(512, 1)
void persist_kernel(const float* __restrict__ x,
                    const us* __restrict__ Wp0, const us* __restrict__ Wp1,
                    const us* __restrict__ Wpf1, const us* __restrict__ Wpf2,
                    const float* __restrict__ bs0, const float* __restrict__ bs1,
                    const float* __restrict__ fc1_b, const float* __restrict__ fc2_b,
                    const float* __restrict__ fc3_w, const float* __restrict__ fc3_b,
                    us* hp0_0, us* hp0_1, us* hp1_0, us* hp1_1,
                    float* c0, float* c1, us* y1p, float* y2,
                    float* out, int* cnt)
{
  __shared__ __align__(16) us Ash[3][4096];
  __shared__ __align__(16) float Gs[2][4][64][16];   // [pset][strip][row][col]

  const int tid = threadIdx.x;
  const int bid = blockIdx.x;
  const int w = tid >> 6, l = tid & 63;
  const int strip = w & 3, pset = w >> 2;
  const int m = bid >> 5;                      // group 0..7 (64 rows)
  const int lb = bid & 31;                     // group-local WG id
  const int jb = (lb & 7) * 4 + (lb >> 3);     // h-col slice 0..31
  const int row0 = m * 64;
  const int j0 = jb * 16;
  const int base31 = j0 & 31;

  const us* WpJ0 = Wp0 + (size_t)jb * 17 * 4096;
  const us* WpJ1 = Wp1 + (size_t)jb * 32 * 4096;

  int ph = 0;
  auto gbar = [&]() {
    ++ph;
    WAITVM(0);
    __syncthreads();
    if (tid == 0) {
      __hip_atomic_fetch_add(&cnt[m * 64], 1, __ATOMIC_RELEASE,
                             __HIP_MEMORY_SCOPE_AGENT);
      while (__hip_atomic_load(&cnt[m * 64], __ATOMIC_RELAXED,
                               __HIP_MEMORY_SCOPE_AGENT) < 32 * ph)
        __builtin_amdgcn_s_sleep(1);
      __builtin_amdgcn_fence(__ATOMIC_ACQUIRE, "workgroup");
    }
    __syncthreads();
  };

  // ---------- fused LSTM phase: {L1(t-1) if DO1} + {L0(t) if DO0} ----------
  auto fused = [&](bool DO1, bool DO0, int t, bool use_fb, int kidx) {
    const us* h0prev = ((t + 1) & 1) ? hp0_1 : hp0_0;
    const us* h1prev = (t & 1) ? hp1_1 : hp1_0;
    us* h1w = ((t + 1) & 1) ? hp1_1 : hp1_0;
    us* h0w = (t & 1) ? hp0_1 : hp0_0;

    f32x4 acc0[4], acc1[4];
    #pragma unroll
    for (int mf = 0; mf < 4; ++mf) {
      acc0[mf] = {0.f, 0.f, 0.f, 0.f};
      acc1[mf] = {0.f, 0.f, 0.f, 0.f};
    }
    const int NP = DO1 ? 32 : 16;
    SetA A0s, A1s, A2s, A3s;
    SetB B0s, B1s;   // B0s: even chunks (pset0), B1s: odd (pset1)

    auto issA = [&](int c, SetA& R) {
      if (c >= NP) return;
      const us* a = ((c < 16) ? h0prev : h1prev) + (size_t)(m * 16 + (c & 15)) * 4096;
      R.a0 = ald8(a + tid * 8);
      R.a1 = ald8(a + tid * 8 + 4);
    };
    auto issB = [&](int c, SetB& R) {
      if (c >= NP || (c & 1) != pset) return;
      if (DO1) { const us* b = WpJ1 + (size_t)c * 4096 + strip * 1024 + l * 8;
                 R.b10 = *(const s16x8*)(b);
                 R.b11 = *(const s16x8*)(b + 512); }
      if (DO0 && c < 16) { const us* b = WpJ0 + (size_t)(c + 1) * 4096 + strip * 1024 + l * 8;
                 R.b00 = *(const s16x8*)(b);
                 R.b01 = *(const s16x8*)(b + 512); }
    };
    auto wrtA = [&](int c, SetA& R) {
      if (c >= NP) return;
      int sl = c % 3;
      *(ull*)&Ash[sl][tid * 8] = R.a0;
      *(ull*)&Ash[sl][tid * 8 + 4] = R.a1;
    };
    auto lcomp = [&](int kc, SetB& B, bool c1on, bool c0on) {
      if ((kc & 1) != pset) return;
      int sl = kc % 3;
      #pragma unroll
      for (int mf = 0; mf < 4; ++mf) {
        s16x8 Ah = *(const s16x8*)&Ash[sl][(mf * 2 + 0) * 512 + l * 8];
        s16x8 Al = *(const s16x8*)&Ash[sl][(mf * 2 + 1) * 512 + l * 8];
        if (c1on) {
          acc1[mf] = __builtin_amdgcn_mfma_f32_16x16x32_bf16(Ah, B.b10, acc1[mf], 0, 0, 0);
          acc1[mf] = __builtin_amdgcn_mfma_f32_16x16x32_bf16(Ah, B.b11, acc1[mf], 0, 0, 0);
          acc1[mf] = __builtin_amdgcn_mfma_f32_16x16x32_bf16(Al, B.b10, acc1[mf], 0, 0, 0);
        }
        if (c0on) {
          acc0[mf] = __builtin_amdgcn_mfma_f32_16x16x32_bf16(Ah, B.b00, acc0[mf], 0, 0, 0);
          acc0[mf] = __builtin_amdgcn_mfma_f32_16x16x32_bf16(Ah, B.b01, acc0[mf], 0, 0, 0);
          acc0[mf] = __builtin_amdgcn_mfma_f32_16x16x32_bf16(Al, B.b00, acc0[mf], 0, 0, 0);
        }
      }
    };

    // prologue: A depth-4, period-4 rotation (r12-proven); B parity depth-1 each
    issA(0, A0s); issA(1, A1s); issA(2, A2s); issA(3, A3s);
    wrtA(0, A0s); issA(4, A0s);
    wrtA(1, A1s); issA(5, A1s);
    issB(0, B0s); issB(1, B1s);
    __syncthreads();
    for (int base = 0; base < NP; base += 4) {
      { int kc = base + 0; lcomp(kc, B0s, DO1, DO0 && kc < 16);
        issB(kc + 2, B0s);
        wrtA(kc + 2, A2s); issA(kc + 6, A2s); __syncthreads(); }
      { int kc = base + 1; lcomp(kc, B1s, DO1, DO0 && kc < 16);
        issB(kc + 2, B1s);
        wrtA(kc + 2, A3s); issA(kc + 6, A3s); __syncthreads(); }
      { int kc = base + 2; lcomp(kc, B0s, DO1, DO0 && kc < 16);
        issB(kc + 2, B0s);
        wrtA(kc + 2, A0s); issA(kc + 6, A0s); __syncthreads(); }
      { int kc = base + 3; lcomp(kc, B1s, DO1, DO0 && kc < 16);
        issB(kc + 2, B1s);
        wrtA(kc + 2, A1s); issA(kc + 6, A1s); __syncthreads(); }
    }

    if (DO0) {  // x chunk (L0 weight chunk 0): staged by all, computed by pset0
      SetB Bx;
      { const us* b = WpJ0 + strip * 1024 + l * 8;
        Bx.b00 = *(const s16x8*)(b);
        Bx.b01 = *(const s16x8*)(b + 512); }
      int srow = tid >> 3, k0 = (tid & 7) * 4;
      const float* xp = x + (size_t)(row0 + srow) * (T * Fdim) + (size_t)t * Fdim + k0;
      float v[4];
      #pragma unroll
      for (int i = 0; i < 4; ++i) v[i] = xp[i];
      if (use_fb && k0 == 4) {
        const float* op = out + (size_t)(row0 + srow) * OSTR + kidx * 2;
        v[0] = __hip_atomic_load(op, __ATOMIC_RELAXED, __HIP_MEMORY_SCOPE_AGENT);
        v[1] = __hip_atomic_load(op + 1, __ATOMIC_RELAXED, __HIP_MEMORY_SCOPE_AGENT);
      }
      s16x4 h4, l4;
      #pragma unroll
      for (int i = 0; i < 4; ++i) {
        us hh = f2bf(v[i]);
        h4[i] = (short)hh;
        l4[i] = (short)f2bf(v[i] - bf2f(hh));
      }
      int lane = (k0 >> 3) * 16 + (srow & 15), i0 = k0 & 7, mf2 = srow >> 4;
      *(s16x4*)&Ash[0][(mf2 * 2 + 0) * 512 + lane * 8 + i0] = h4;
      *(s16x4*)&Ash[0][(mf2 * 2 + 1) * 512 + lane * 8 + i0] = l4;
      __syncthreads();
      if (pset == 0) {
        #pragma unroll
        for (int mf = 0; mf < 4; ++mf) {
          s16x8 Ah = *(const s16x8*)&Ash[0][(mf * 2 + 0) * 512 + l * 8];
          s16x8 Al = *(const s16x8*)&Ash[0][(mf * 2 + 1) * 512 + l * 8];
          acc0[mf] = __builtin_amdgcn_mfma_f32_16x16x32_bf16(Ah, Bx.b00, acc0[mf], 0, 0, 0);
          acc0[mf] = __builtin_amdgcn_mfma_f32_16x16x32_bf16(Ah, Bx.b01, acc0[mf], 0, 0, 0);
          acc0[mf] = __builtin_amdgcn_mfma_f32_16x16x32_bf16(Al, Bx.b00, acc0[mf], 0, 0, 0);
        }
      }
    }

    // epilogue: both psets stash raw gates -> merge -> cell -> packed h write
    auto epi = [&](f32x4* acc, const float* bsum, float* cst, us* hw) {
      __syncthreads();
      float bsv = (pset == 0) ? bsum[strip * 512 + j0 + (l & 15)] : 0.f;
      #pragma unroll
      for (int mf = 0; mf < 4; ++mf)
        #pragma unroll
        for (int r = 0; r < 4; ++r)
          Gs[pset][strip][mf * 16 + (l >> 4) * 4 + r][l & 15] = acc[mf][r] + bsv;
      __syncthreads();
      if (tid < 256) {
        int r = tid >> 2, cc0 = (tid & 3) * 4;
        float gvi[4], gvf[4], gvg[4], gvo[4], cv[4], cn[4], hv[4];
        #pragma unroll
        for (int q = 0; q < 4; ++q) {
          gvi[q] = Gs[0][0][r][cc0 + q] + Gs[1][0][r][cc0 + q];
          gvf[q] = Gs[0][1][r][cc0 + q] + Gs[1][1][r][cc0 + q];
          gvg[q] = Gs[0][2][r][cc0 + q] + Gs[1][2][r][cc0 + q];
          gvo[q] = Gs[0][3][r][cc0 + q] + Gs[1][3][r][cc0 + q];
        }
        size_t cix = (size_t)(row0 + r) * H + j0 + cc0;
        float4 cold = *(const float4*)&cst[cix];
        cv[0] = cold.x; cv[1] = cold.y; cv[2] = cold.z; cv[3] = cold.w;
        #pragma unroll
        for (int q = 0; q < 4; ++q) {
          float c2 = sigf(gvf[q]) * cv[q] + sigf(gvi[q]) * tanhf(gvg[q]);
          cn[q] = c2;
          hv[q] = sigf(gvo[q]) * tanhf(c2);
        }
        *(float4*)&cst[cix] = make_float4(cn[0], cn[1], cn[2], cn[3]);
        int kk = base31 + cc0;
        int kg = kk >> 3, i0 = kk & 7;
        int mf = r >> 4;
        int lane2 = kg * 16 + (r & 15);
        us* bb = hw + (size_t)(m * 16 + (j0 >> 5)) * 4096;
        U8 hh, hl;
        #pragma unroll
        for (int q = 0; q < 4; ++q) {
          us h2 = f2bf(hv[q]);
          hh.v4[q] = (short)h2;
          hl.v4[q] = (short)f2bf(hv[q] - bf2f(h2));
        }
        ast8(bb + (size_t)(mf * 2 + 0) * 512 + lane2 * 8 + i0, hh.u);
        ast8(bb + (size_t)(mf * 2 + 1) * 512 + lane2 * 8 + i0, hl.u);
      }
      __syncthreads();
    };
    if (DO1) epi(acc1, bs1, c1, h1w);
    if (DO0) epi(acc0, bs0, c0, h0w);
  };

  // ---------- head GEMM: 16 of 32 WGs, 32 rows x 64 cols, parity-split ----------
  auto headg = [&](const us* apack, const us* Wp, const float* bias,
                   float* yf, us* yp) {
    if (lb < 16) {
      const int mhl = lb >> 3, cb = lb & 7;
      const int hrow0 = row0 + mhl * 32, hj0 = cb * 64;
      const int wm = w & 1, wn = (w >> 1) & 1;   // pset = w>>2 (outer)
      f32x4 hacc[2];
      hacc[0] = {0.f, 0.f, 0.f, 0.f};
      hacc[1] = {0.f, 0.f, 0.f, 0.f};
      SetA HA0, HA1, HA2, HA3;
      HSetB HB0, HB1;
      auto hissA = [&](int c, SetA& R) {
        if (c >= 16) return;
        const us* a = apack + (size_t)(m * 16 + c) * 4096 + mhl * 2048;
        R.a0 = ald8(a + (tid & 255) * 8);
        R.a1 = ald8(a + (tid & 255) * 8 + 4);
      };
      auto hissB = [&](int c, HSetB& R) {
        if (c >= 16 || (c & 1) != pset) return;
        const us* b = Wp + (size_t)(cb * 16 + c) * 4096 + wn * 2048 + l * 8;
        R.b0h = *(const s16x8*)(b);
        R.b0l = *(const s16x8*)(b + 512);
        R.b1h = *(const s16x8*)(b + 1024);
        R.b1l = *(const s16x8*)(b + 1536);
      };
      auto hwrtA = [&](int c, SetA& R) {
        if (c >= 16 || tid >= 256) return;
        int sl = c % 3;
        *(ull*)&Ash[sl][tid * 8] = R.a0;
        *(ull*)&Ash[sl][tid * 8 + 4] = R.a1;
      };
      auto hcmp = [&](int kc, HSetB& B) {
        if ((kc & 1) != pset) return;
        int sl = kc % 3;
        s16x8 Ah = *(const s16x8*)&Ash[sl][(wm * 2 + 0) * 512 + l * 8];
        s16x8 Al = *(const s16x8*)&Ash[sl][(wm * 2 + 1) * 512 + l * 8];
        hacc[0] = __builtin_amdgcn_mfma_f32_16x16x32_bf16(Ah, B.b0h, hacc[0], 0, 0, 0);
        hacc[0] = __builtin_amdgcn_mfma_f32_16x16x32_bf16(Ah, B.b0l, hacc[0], 0, 0, 0);
        hacc[0] = __builtin_amdgcn_mfma_f32_16x16x32_bf16(Al, B.b0h, hacc[0], 0, 0, 0);
        hacc[1] = __builtin_amdgcn_mfma_f32_16x16x32_bf16(Ah, B.b1h, hacc[1], 0, 0, 0);
        hacc[1] = __builtin_amdgcn_mfma_f32_16x16x32_bf16(Ah, B.b1l, hacc[1], 0, 0, 0);
        hacc[1] = __builtin_amdgcn_mfma_f32_16x16x32_bf16(Al, B.b1h, hacc[1], 0, 0, 0);
      };
      hissA(0, HA0); hissA(1, HA1); hissA(2, HA2); hissA(3, HA3);
      hwrtA(0, HA0); hissA(4, HA0);
      hwrtA(1, HA1); hissA(5, HA1);
      hissB(0, HB0); hissB(1, HB1);
      __syncthreads();
      for (int base = 0; base < 16; base += 4) {
        { int kc = base + 0; hcmp(kc, HB0); hissB(kc + 2, HB0);
          hwrtA(kc + 2, HA2); hissA(kc + 6, HA2); __syncthreads(); }
        { int kc = base + 1; hcmp(kc, HB1); hissB(kc + 2, HB1);
          hwrtA(kc + 2, HA3); hissA(kc + 6, HA3); __syncthreads(); }
        { int kc = base + 2; hcmp(kc, HB0); hissB(kc + 2, HB0);
          hwrtA(kc + 2, HA0); hissA(kc + 6, HA0); __syncthreads(); }
        { int kc = base + 3; hcmp(kc, HB1); hissB(kc + 2, HB1);
          hwrtA(kc + 2, HA1); hissA(kc + 6, HA1); __syncthreads(); }
      }
      __syncthreads();
      float* GsF = (float*)Gs;   // [pset][32][64] raw accum
      #pragma unroll
      for (int nf = 0; nf < 2; ++nf)
        #pragma unroll
        for (int rq = 0; rq < 4; ++rq) {
          int rr = wm * 16 + (l >> 4) * 4 + rq;
          int ccl = wn * 32 + nf * 16 + (l & 15);
          GsF[pset * 2048 + rr * 64 + ccl] = hacc[nf][rq];
        }
      __syncthreads();
      if (tid < 256) {  // merge + bias + gelu, in place into GsF[0..2047]
        #pragma unroll
        for (int i = 0; i < 8; ++i) {
          int idx = tid * 8 + i;
          int cc = idx & 63;
          GsF[idx] = geluf(GsF[idx] + GsF[2048 + idx] + bias[hj0 + cc]);
        }
      }
      __syncthreads();
      if (yp) {
        if (tid < 256) {
          int chunk = tid >> 7, tt = tid & 127;
          int mf_loc = tt >> 6, lane = tt & 63;
          int row = mf_loc * 16 + (lane & 15);
          int kg = lane >> 4;
          S8 hi, lo;
          #pragma unroll
          for (int i = 0; i < 8; ++i) {
            float v = GsF[row * 64 + chunk * 32 + kg * 8 + i];
            us hh = f2bf(v);
            hi.v[i] = (short)hh;
            lo.v[i] = (short)f2bf(v - bf2f(hh));
          }
          us* dst = yp + ((size_t)m * 16 + (cb * 2 + chunk)) * 4096 + mhl * 2048;
          ast8(dst + (size_t)(mf_loc * 2 + 0) * 512 + lane * 8, hi.u[0]);
          ast8(dst + (size_t)(mf_loc * 2 + 0) * 512 + lane * 8 + 4, hi.u[1]);
          ast8(dst + (size_t)(mf_loc * 2 + 1) * 512 + lane * 8, lo.u[0]);
          ast8(dst + (size_t)(mf_loc * 2 + 1) * 512 + lane * 8 + 4, lo.u[1]);
        }
      } else {
        if (tid < 256) {
          int rr = tid >> 3, cc0 = (tid & 7) * 8;
          float* dst = yf + (size_t)(hrow0 + rr) * 512 + hj0 + cc0;
          #pragma unroll
          for (int i = 0; i < 4; ++i) {
            U8 p;
            p.f[0] = GsF[rr * 64 + cc0 + i * 2];
            p.f[1] = GsF[rr * 64 + cc0 + i * 2 + 1];
            ast8(dst + i * 2, p.u);
          }
        }
      }
      __syncthreads();
    }
  };

  // ---------- fc3: 2 rows per WG, waves 0-3 (one wave = one (row, o) pair) ----------
  auto fc3p = [&](int kidx) {
    if (w < 4) {
      int rloc = w >> 1, o = w & 1;
      int row = row0 + lb * 2 + rloc;
      const float* src = y2 + (size_t)row * 512 + l * 8;
      const float* wt = fc3_w + o * 512 + l * 8;
      U8 v0, v1, v2, v3;
      v0.u = ald8(src); v1.u = ald8(src + 2);
      v2.u = ald8(src + 4); v3.u = ald8(src + 6);
      float s = v0.f[0] * wt[0] + v0.f[1] * wt[1] + v1.f[0] * wt[2] + v1.f[1] * wt[3]
              + v2.f[0] * wt[4] + v2.f[1] * wt[5] + v3.f[0] * wt[6] + v3.f[1] * wt[7];
      #pragma unroll
      for (int d = 32; d > 0; d >>= 1) s += __shfl_down(s, d, 64);
      if (l == 0)
        __hip_atomic_store(out + (size_t)row * OSTR + kidx * 2 + o,
                           s + fc3_b[o], __ATOMIC_RELAXED, __HIP_MEMORY_SCOPE_AGENT);
    }
    __syncthreads();
  };

  // ================= schedule (8 independent groups) =================
  for (int t = 0; t < 64; ++t) { fused(t > 0, true, t, false, 0); gbar(); }
  fused(true, false, 64, false, 0); gbar();   // L1(63)

  for (int kidx = 0; kidx < 17; ++kidx) {
    const us* h1cur = ((63 + kidx) & 1) ? hp1_1 : hp1_0;
    headg(h1cur, Wpf1, fc1_b, nullptr, y1p); gbar();
    headg(y1p, Wpf2, fc2_b, y2, nullptr); gbar();
    fc3p(kidx);
    if (kidx < 16) {
      gbar();
      fused(false, true, 64 + kidx, true, kidx); gbar();
      fused(true, false, 65 + kidx, false, 0); gbar();
    }
  }
}

} // namespace

extern "C" void kernel_launch(void* const* d_in, const int* in_sizes, int n_in,
                              void* d_out, int out_size, void* d_ws, size_t ws_size,
                              hipStream_t stream) {
  const float* x     = (const float*)d_in[0];
  const float* w_ih0 = (const float*)d_in[1];
  const float* w_hh0 = (const float*)d_in[2];
  const float* b_ih0 = (const float*)d_in[3];
  const float* b_hh0 = (const float*)d_in[4];
  const float* w_ih1 = (const float*)d_in[5];
  const float* w_hh1 = (const float*)d_in[6];
  const float* b_ih1 = (const float*)d_in[7];
  const float* b_hh1 = (const float*)d_in[8];
  const float* fc1_w = (const float*)d_in[9];
  const float* fc1_b = (const float*)d_in[10];
  const float* fc2_w = (const float*)d_in[11];
  const float* fc2_b = (const float*)d_in[12];
  const float* fc3_w = (const float*)d_in[13];
  const float* fc3_b = (const float*)d_in[14];
  float* out = (float*)d_out;
  char* wsb = (char*)d_ws;

  constexpr size_t MB = 1048576;
  constexpr size_t O_WP0  = 0;
  constexpr size_t O_WP1  = 4456448;
  constexpr size_t O_WPF1 = O_WP1 + 8388608;
  constexpr size_t O_WPF2 = O_WPF1 + MB;
  constexpr size_t O_BS0  = O_WPF2 + MB;
  constexpr size_t O_BS1  = O_BS0 + 8192;
  constexpr size_t O_CNT  = O_BS1 + 8192;
  constexpr size_t O_HP0B = O_CNT + 4096;           // hp0_1 (zeroed)
  constexpr size_t O_HP1B = O_HP0B + MB;            // hp1_1 (zeroed)
  constexpr size_t O_C0   = O_HP1B + MB;            // c0 (zeroed)
  constexpr size_t O_C1   = O_C0 + MB;              // c1 (zeroed)
  constexpr size_t O_HP0A = O_C1 + MB;
  constexpr size_t O_HP1A = O_HP0A + MB;
  constexpr size_t O_Y1P  = O_HP1A + MB;
  constexpr size_t O_Y2   = O_Y1P + MB;

  us* Wp0  = (us*)(wsb + O_WP0);
  us* Wp1  = (us*)(wsb + O_WP1);
  us* Wpf1 = (us*)(wsb + O_WPF1);
  us* Wpf2 = (us*)(wsb + O_WPF2);
  float* bs0 = (float*)(wsb + O_BS0);
  float* bs1 = (float*)(wsb + O_BS1);
  int* cnt   = (int*)(wsb + O_CNT);
  us* hp0_1 = (us*)(wsb + O_HP0B);
  us* hp1_1 = (us*)(wsb + O_HP1B);
  float* c0 = (float*)(wsb + O_C0);
  float* c1 = (float*)(wsb + O_C1);
  us* hp0_0 = (us*)(wsb + O_HP0A);
  us* hp1_0 = (us*)(wsb + O_HP1A);
  us* y1p   = (us*)(wsb + O_Y1P);
  float* y2 = (float*)(wsb + O_Y2);

  pack_w_kernel<<<dim3(32 * 17), 256, 0, stream>>>(w_ih0, w_hh0, 32, 512, 17, 0, Wp0);
  pack_w_kernel<<<dim3(32 * 32), 256, 0, stream>>>(w_ih1, w_hh1, 512, 512, 32, 0, Wp1);
  pack_w_kernel<<<dim3(8 * 16), 256, 0, stream>>>(fc1_w, fc1_w, 512, 512, 16, 1, Wpf1);
  pack_w_kernel<<<dim3(8 * 16), 256, 0, stream>>>(fc2_w, fc2_w, 512, 512, 16, 1, Wpf2);
  bsum_kernel<<<dim3(16), 256, 0, stream>>>(b_ih0, b_hh0, b_ih1, b_hh1, bs0, bs1);
  hipMemsetAsync(wsb + O_CNT, 0, 4096 + 4 * MB, stream);

  persist_kernel<<<dim3(256), dim3(512), 0, stream>>>(
      x, Wp0, Wp1, Wpf1, Wpf2, bs0, bs1, fc1_b, fc2_b, fc3_w, fc3_b,
      hp0_0, hp0_1, hp1_0, hp1_1, c0, c1, y1p, y2, out, cnt);
}

// Round 15
// 2531.454 us; speedup vs baseline: 1.1670x; 1.1670x over previous
//
#include <hip/hip_runtime.h>
#include <math.h>

typedef short s16x4 __attribute__((ext_vector_type(4)));
typedef short s16x8 __attribute__((ext_vector_type(8)));
typedef float f32x4 __attribute__((ext_vector_type(4)));
typedef unsigned short us;
typedef unsigned long long ull;

#define WAITVM(N) do { asm volatile("s_waitcnt vmcnt(" #N ")" ::: "memory"); __builtin_amdgcn_sched_barrier(0); } while (0)

namespace {
constexpr int T = 80, Fdim = 32, H = 512, OSTR = 34;

__device__ __forceinline__ us f2bf(float f) {
  union { float f; unsigned u; } x; x.f = f;
  unsigned u = x.u; u += 0x7fffu + ((u >> 16) & 1u);
  return (us)(u >> 16);
}
__device__ __forceinline__ float bf2f(us s) {
  union { unsigned u; float f; } x; x.u = ((unsigned)s) << 16; return x.f;
}
__device__ __forceinline__ float sigf(float v) { return 1.f / (1.f + expf(-v)); }
__device__ __forceinline__ float geluf(float v) {
  return 0.5f * v * (1.f + erff(v * 0.70710678118654752f));
}

__device__ __forceinline__ ull ald8(const void* p) {
  return __hip_atomic_load((const ull*)p, __ATOMIC_RELAXED, __HIP_MEMORY_SCOPE_AGENT);
}
__device__ __forceinline__ void ast8(void* p, ull v) {
  __hip_atomic_store((ull*)p, v, __ATOMIC_RELAXED, __HIP_MEMORY_SCOPE_AGENT);
}

union U8 { ull u; s16x4 v4; float f[2]; };
union S8 { s16x8 v; ull u[2]; };

struct SetA { ull a0, a1, a2, a3; };
struct SetB { s16x8 b10, b11, b00, b01; };
struct HSetA { ull a0, a1; };
struct HSetB { s16x8 b0h, b0l, b1h, b1l; };

// ---------------- weight pre-pack (unchanged) ----------------
__global__ __launch_bounds__(256)
void pack_w_kernel(const float* __restrict__ w1, const float* __restrict__ w2,
                   int K1, int K2, int NKC, int head, us* __restrict__ dst) {
  int bid = blockIdx.x;
  int jb = bid / NKC, kc = bid % NKC;
  int tid = threadIdx.x;
  int strip = tid >> 6, l = tid & 63;
  int nl = l & 15, kg = l >> 4;
  int n = head ? (jb * 64 + strip * 16 + nl) : (strip * 512 + jb * 16 + nl);
  s16x8 h8, l8;
  #pragma unroll
  for (int i = 0; i < 8; ++i) {
    int k = kc * 32 + kg * 8 + i;
    float v = (k < K1) ? w1[(size_t)n * K1 + k] : w2[(size_t)n * K2 + (k - K1)];
    us h = f2bf(v);
    h8[i] = (short)h;
    l8[i] = (short)f2bf(v - bf2f(h));
  }
  size_t base = (size_t)bid * 4096;
  *(s16x8*)&dst[base + (size_t)(strip * 2 + 0) * 512 + l * 8] = h8;
  *(s16x8*)&dst[base + (size_t)(strip * 2 + 1) * 512 + l * 8] = l8;
}

__global__ __launch_bounds__(256)
void bsum_kernel(const float* bi0, const float* bh0, const float* bi1, const float* bh1,
                 float* bs0, float* bs1) {
  int i = blockIdx.x * 256 + threadIdx.x;
  if (i < 2048) bs0[i] = bi0[i] + bh0[i];
  else { int j = i - 2048; bs1[j] = bi1[j] + bh1[j]; }
}

// ---------------- persistent whole-model kernel ----------------
// 256 WGs = 8 independent groups (64 batch rows) x 32 WGs (16 h-cols).
// B direct L2->reg (4-set rotation); A through 8 LDS slots, 2 barriers / 4 chunks.
__global__ __launch_bounds__(256, 1)
void persist_kernel(const float* __restrict__ x,
                    const us* __restrict__ Wp0, const us* __restrict__ Wp1,
                    const us* __restrict__ Wpf1, const us* __restrict__ Wpf2,
                    const float* __restrict__ bs0, const float* __restrict__ bs1,
                    const float* __restrict__ fc1_b, const float* __restrict__ fc2_b,
                    const float* __restrict__ fc3_w, const float* __restrict__ fc3_b,
                    us* hp0_0, us* hp0_1, us* hp1_0, us* hp1_1,
                    float* c0, float* c1, us* y1p, float* y2,
                    float* out, int* cnt)
{
  __shared__ __align__(16) us Ash[8][4096];
  __shared__ __align__(16) float Gs[4][64][16];

  const int tid = threadIdx.x;
  const int bid = blockIdx.x;
  const int w = tid >> 6, l = tid & 63;
  const int m = bid >> 5;                      // group 0..7 (64 rows)
  const int lb = bid & 31;                     // group-local WG id
  const int jb = (lb & 7) * 4 + (lb >> 3);     // h-col slice 0..31
  const int row0 = m * 64;
  const int j0 = jb * 16;
  const int base31 = j0 & 31;

  const us* WpJ0 = Wp0 + (size_t)jb * 17 * 4096;
  const us* WpJ1 = Wp1 + (size_t)jb * 32 * 4096;

  int ph = 0;
  auto gbar = [&]() {
    ++ph;
    WAITVM(0);
    __syncthreads();
    if (tid == 0) {
      __hip_atomic_fetch_add(&cnt[m * 64], 1, __ATOMIC_RELEASE,
                             __HIP_MEMORY_SCOPE_AGENT);
      while (__hip_atomic_load(&cnt[m * 64], __ATOMIC_RELAXED,
                               __HIP_MEMORY_SCOPE_AGENT) < 32 * ph)
        __builtin_amdgcn_s_sleep(1);
      __builtin_amdgcn_fence(__ATOMIC_ACQUIRE, "workgroup");
    }
    __syncthreads();
  };

  // ---------- fused LSTM phase: {L1(t-1) if DO1} + {L0(t) if DO0} ----------
  auto fused = [&](bool DO1, bool DO0, int t, bool use_fb, int kidx) {
    const us* h0prev = ((t + 1) & 1) ? hp0_1 : hp0_0;
    const us* h1prev = (t & 1) ? hp1_1 : hp1_0;
    us* h1w = ((t + 1) & 1) ? hp1_1 : hp1_0;
    us* h0w = (t & 1) ? hp0_1 : hp0_0;

    f32x4 acc0[4], acc1[4];
    #pragma unroll
    for (int mf = 0; mf < 4; ++mf) {
      acc0[mf] = {0.f, 0.f, 0.f, 0.f};
      acc1[mf] = {0.f, 0.f, 0.f, 0.f};
    }
    const int NP = DO1 ? 32 : 16;
    SetA A0s, A1s, A2s, A3s;
    SetB B0s, B1s, B2s, B3s;

    auto issA = [&](int c, SetA& R) {
      if (c >= NP) return;
      const us* a = ((c < 16) ? h0prev : h1prev) + (size_t)(m * 16 + (c & 15)) * 4096;
      R.a0 = ald8(a + tid * 8);
      R.a1 = ald8(a + tid * 8 + 4);
      R.a2 = ald8(a + 2048 + tid * 8);
      R.a3 = ald8(a + 2048 + tid * 8 + 4);
    };
    auto issB = [&](int c, SetB& R) {
      if (c >= NP) return;
      if (DO1) { const us* b = WpJ1 + (size_t)c * 4096 + w * 1024 + l * 8;
                 R.b10 = *(const s16x8*)(b);
                 R.b11 = *(const s16x8*)(b + 512); }
      if (DO0 && c < 16) { const us* b = WpJ0 + (size_t)(c + 1) * 4096 + w * 1024 + l * 8;
                 R.b00 = *(const s16x8*)(b);
                 R.b01 = *(const s16x8*)(b + 512); }
    };
    auto wrtA = [&](int c, SetA& R) {
      if (c >= NP) return;
      int sl = c & 7;
      *(ull*)&Ash[sl][tid * 8] = R.a0;
      *(ull*)&Ash[sl][tid * 8 + 4] = R.a1;
      *(ull*)&Ash[sl][2048 + tid * 8] = R.a2;
      *(ull*)&Ash[sl][2048 + tid * 8 + 4] = R.a3;
    };
    auto lcomp = [&](int kc, SetB& B, bool c1on, bool c0on) {
      int sl = kc & 7;
      #pragma unroll
      for (int mf = 0; mf < 4; ++mf) {
        s16x8 Ah = *(const s16x8*)&Ash[sl][(mf * 2 + 0) * 512 + l * 8];
        s16x8 Al = *(const s16x8*)&Ash[sl][(mf * 2 + 1) * 512 + l * 8];
        if (c1on) {
          acc1[mf] = __builtin_amdgcn_mfma_f32_16x16x32_bf16(Ah, B.b10, acc1[mf], 0, 0, 0);
          acc1[mf] = __builtin_amdgcn_mfma_f32_16x16x32_bf16(Ah, B.b11, acc1[mf], 0, 0, 0);
          acc1[mf] = __builtin_amdgcn_mfma_f32_16x16x32_bf16(Al, B.b10, acc1[mf], 0, 0, 0);
        }
        if (c0on) {
          acc0[mf] = __builtin_amdgcn_mfma_f32_16x16x32_bf16(Ah, B.b00, acc0[mf], 0, 0, 0);
          acc0[mf] = __builtin_amdgcn_mfma_f32_16x16x32_bf16(Ah, B.b01, acc0[mf], 0, 0, 0);
          acc0[mf] = __builtin_amdgcn_mfma_f32_16x16x32_bf16(Al, B.b00, acc0[mf], 0, 0, 0);
        }
      }
    };

    // prologue: A chunks 0..3 staged+written, 4..7 in flight; B chunks 0..3 in flight
    issA(0, A0s); issA(1, A1s); issA(2, A2s); issA(3, A3s);
    issB(0, B0s); issB(1, B1s); issB(2, B2s); issB(3, B3s);
    wrtA(0, A0s); wrtA(1, A1s); wrtA(2, A2s); wrtA(3, A3s);
    issA(4, A0s); issA(5, A1s); issA(6, A2s); issA(7, A3s);
    __syncthreads();
    // steady state: per 4-chunk block, 2 barriers
    for (int base = 0; base < NP; base += 4) {
      { int kc = base + 0; lcomp(kc, B0s, DO1, DO0 && kc < 16); issB(kc + 4, B0s); }
      { int kc = base + 1; lcomp(kc, B1s, DO1, DO0 && kc < 16); issB(kc + 4, B1s); }
      { int kc = base + 2; lcomp(kc, B2s, DO1, DO0 && kc < 16); issB(kc + 4, B2s); }
      { int kc = base + 3; lcomp(kc, B3s, DO1, DO0 && kc < 16); issB(kc + 4, B3s); }
      __syncthreads();               // all reads of slots (base..base+3)&7 done
      wrtA(base + 4, A0s); wrtA(base + 5, A1s);
      wrtA(base + 6, A2s); wrtA(base + 7, A3s);
      issA(base + 8, A0s); issA(base + 9, A1s);
      issA(base + 10, A2s); issA(base + 11, A3s);
      __syncthreads();               // writes visible for next block
    }

    if (DO0) {  // x chunk (L0 weight chunk 0), B direct from L2
      SetB Bx;
      { const us* b = WpJ0 + w * 1024 + l * 8;
        Bx.b00 = *(const s16x8*)(b);
        Bx.b01 = *(const s16x8*)(b + 512); }
      int srow = tid >> 2, skg = tid & 3;
      const float* xp = x + (size_t)(row0 + srow) * (T * Fdim) + (size_t)t * Fdim + skg * 8;
      float v[8];
      #pragma unroll
      for (int i = 0; i < 8; ++i) v[i] = xp[i];
      if (use_fb && skg == 0) {
        const float* op = out + (size_t)(row0 + srow) * OSTR + kidx * 2;
        v[4] = __hip_atomic_load(op, __ATOMIC_RELAXED, __HIP_MEMORY_SCOPE_AGENT);
        v[5] = __hip_atomic_load(op + 1, __ATOMIC_RELAXED, __HIP_MEMORY_SCOPE_AGENT);
      }
      s16x8 h8, l8;
      #pragma unroll
      for (int i = 0; i < 8; ++i) {
        us hh = f2bf(v[i]);
        h8[i] = (short)hh;
        l8[i] = (short)f2bf(v[i] - bf2f(hh));
      }
      int slane = skg * 16 + (srow & 15), smf = srow >> 4;
      *(s16x8*)&Ash[0][(smf * 2 + 0) * 512 + slane * 8] = h8;
      *(s16x8*)&Ash[0][(smf * 2 + 1) * 512 + slane * 8] = l8;
      __syncthreads();
      lcomp(0, Bx, false, true);
    }

    // epilogue: stash gates -> cell -> packed coherent h write
    auto epi = [&](f32x4* acc, const float* bsum, float* cst, us* hw) {
      __syncthreads();
      float bsv = bsum[w * 512 + j0 + (l & 15)];
      #pragma unroll
      for (int mf = 0; mf < 4; ++mf)
        #pragma unroll
        for (int r = 0; r < 4; ++r)
          Gs[w][mf * 16 + (l >> 4) * 4 + r][l & 15] = acc[mf][r] + bsv;
      __syncthreads();
      int r = tid >> 2, sub = tid & 3, cc0 = sub * 4;
      float gvi[4], gvf[4], gvg[4], gvo[4], cv[4], cn[4], hv[4];
      #pragma unroll
      for (int q = 0; q < 4; ++q) {
        gvi[q] = Gs[0][r][cc0 + q]; gvf[q] = Gs[1][r][cc0 + q];
        gvg[q] = Gs[2][r][cc0 + q]; gvo[q] = Gs[3][r][cc0 + q];
      }
      size_t cix = (size_t)(row0 + r) * H + j0 + cc0;
      float4 cold = *(const float4*)&cst[cix];
      cv[0] = cold.x; cv[1] = cold.y; cv[2] = cold.z; cv[3] = cold.w;
      #pragma unroll
      for (int q = 0; q < 4; ++q) {
        float c2 = sigf(gvf[q]) * cv[q] + sigf(gvi[q]) * tanhf(gvg[q]);
        cn[q] = c2;
        hv[q] = sigf(gvo[q]) * tanhf(c2);
      }
      *(float4*)&cst[cix] = make_float4(cn[0], cn[1], cn[2], cn[3]);
      int kk = base31 + cc0;
      int kg = kk >> 3, i0 = kk & 7;
      int mf = r >> 4;
      int lane2 = kg * 16 + (r & 15);
      us* bb = hw + (size_t)(m * 16 + (j0 >> 5)) * 4096;
      U8 hh, hl;
      #pragma unroll
      for (int q = 0; q < 4; ++q) {
        us h2 = f2bf(hv[q]);
        hh.v4[q] = (short)h2;
        hl.v4[q] = (short)f2bf(hv[q] - bf2f(h2));
      }
      ast8(bb + (size_t)(mf * 2 + 0) * 512 + lane2 * 8 + i0, hh.u);
      ast8(bb + (size_t)(mf * 2 + 1) * 512 + lane2 * 8 + i0, hl.u);
      __syncthreads();
    };
    if (DO1) epi(acc1, bs1, c1, h1w);
    if (DO0) epi(acc0, bs0, c0, h0w);
  };

  // ---------- head GEMM: group-local, 16 of 32 WGs, 32 rows x 64 cols ----------
  auto headg = [&](const us* apack, const us* Wp, const float* bias,
                   float* yf, us* yp) {
    if (lb < 16) {
      const int mhl = lb >> 3, cb = lb & 7;
      const int hrow0 = row0 + mhl * 32, hj0 = cb * 64;
      const int wm = w >> 1, wn = w & 1;
      f32x4 hacc[2];
      hacc[0] = {0.f, 0.f, 0.f, 0.f};
      hacc[1] = {0.f, 0.f, 0.f, 0.f};
      HSetA HA0, HA1, HA2, HA3;
      HSetB HB0, HB1;
      auto hissA = [&](int c, HSetA& R) {
        if (c >= 16) return;
        const us* a = apack + (size_t)(m * 16 + c) * 4096 + mhl * 2048;
        R.a0 = ald8(a + tid * 8);
        R.a1 = ald8(a + tid * 8 + 4);
      };
      auto hissB = [&](int c, HSetB& R) {
        if (c >= 16) return;
        const us* b = Wp + (size_t)(cb * 16 + c) * 4096 + wn * 2048 + l * 8;
        R.b0h = *(const s16x8*)(b);
        R.b0l = *(const s16x8*)(b + 512);
        R.b1h = *(const s16x8*)(b + 1024);
        R.b1l = *(const s16x8*)(b + 1536);
      };
      auto hwrtA = [&](int c, HSetA& R) {
        if (c >= 16) return;
        int sl = c % 3;
        *(ull*)&Ash[sl][tid * 8] = R.a0;
        *(ull*)&Ash[sl][tid * 8 + 4] = R.a1;
      };
      auto hcmp = [&](int sl, HSetB& B) {
        s16x8 Ah = *(const s16x8*)&Ash[sl][(wm * 2 + 0) * 512 + l * 8];
        s16x8 Al = *(const s16x8*)&Ash[sl][(wm * 2 + 1) * 512 + l * 8];
        hacc[0] = __builtin_amdgcn_mfma_f32_16x16x32_bf16(Ah, B.b0h, hacc[0], 0, 0, 0);
        hacc[0] = __builtin_amdgcn_mfma_f32_16x16x32_bf16(Ah, B.b0l, hacc[0], 0, 0, 0);
        hacc[0] = __builtin_amdgcn_mfma_f32_16x16x32_bf16(Al, B.b0h, hacc[0], 0, 0, 0);
        hacc[1] = __builtin_amdgcn_mfma_f32_16x16x32_bf16(Ah, B.b1h, hacc[1], 0, 0, 0);
        hacc[1] = __builtin_amdgcn_mfma_f32_16x16x32_bf16(Ah, B.b1l, hacc[1], 0, 0, 0);
        hacc[1] = __builtin_amdgcn_mfma_f32_16x16x32_bf16(Al, B.b1h, hacc[1], 0, 0, 0);
      };
      hissA(0, HA0); hissA(1, HA1); hissA(2, HA2); hissA(3, HA3);
      hwrtA(0, HA0); hissA(4, HA0);
      hwrtA(1, HA1); hissA(5, HA1);
      hissB(0, HB0); hissB(1, HB1);
      __syncthreads();
      for (int base = 0; base < 16; base += 4) {
        { int kc = base + 0; hcmp(kc % 3, HB0); hissB(kc + 2, HB0);
          hwrtA(kc + 2, HA2); hissA(kc + 6, HA2); __syncthreads(); }
        { int kc = base + 1; hcmp(kc % 3, HB1); hissB(kc + 2, HB1);
          hwrtA(kc + 2, HA3); hissA(kc + 6, HA3); __syncthreads(); }
        { int kc = base + 2; hcmp(kc % 3, HB0); hissB(kc + 2, HB0);
          hwrtA(kc + 2, HA0); hissA(kc + 6, HA0); __syncthreads(); }
        { int kc = base + 3; hcmp(kc % 3, HB1); hissB(kc + 2, HB1);
          hwrtA(kc + 2, HA1); hissA(kc + 6, HA1); __syncthreads(); }
      }
      __syncthreads();
      float* GsF = (float*)Gs;
      #pragma unroll
      for (int nf = 0; nf < 2; ++nf)
        #pragma unroll
        for (int rq = 0; rq < 4; ++rq) {
          int rr = wm * 16 + (l >> 4) * 4 + rq;
          int ccl = wn * 32 + nf * 16 + (l & 15);
          GsF[rr * 64 + ccl] = geluf(hacc[nf][rq] + bias[hj0 + ccl]);
        }
      __syncthreads();
      if (yp) {
        // packed bf16 hi/lo fragment layout (consumable as next A)
        int chunk = tid >> 7, tt = tid & 127;
        int mf_loc = tt >> 6, lane = tt & 63;
        int row = mf_loc * 16 + (lane & 15);
        int kg = lane >> 4;
        S8 hi, lo;
        #pragma unroll
        for (int i = 0; i < 8; ++i) {
          float v = GsF[row * 64 + chunk * 32 + kg * 8 + i];
          us hh = f2bf(v);
          hi.v[i] = (short)hh;
          lo.v[i] = (short)f2bf(v - bf2f(hh));
        }
        us* dst = yp + ((size_t)m * 16 + (cb * 2 + chunk)) * 4096 + mhl * 2048;
        ast8(dst + (size_t)(mf_loc * 2 + 0) * 512 + lane * 8, hi.u[0]);
        ast8(dst + (size_t)(mf_loc * 2 + 0) * 512 + lane * 8 + 4, hi.u[1]);
        ast8(dst + (size_t)(mf_loc * 2 + 1) * 512 + lane * 8, lo.u[0]);
        ast8(dst + (size_t)(mf_loc * 2 + 1) * 512 + lane * 8 + 4, lo.u[1]);
      } else {
        int rr = tid >> 3, cc0 = (tid & 7) * 8;
        float* dst = yf + (size_t)(hrow0 + rr) * 512 + hj0 + cc0;
        #pragma unroll
        for (int i = 0; i < 4; ++i) {
          U8 p;
          p.f[0] = GsF[rr * 64 + cc0 + i * 2];
          p.f[1] = GsF[rr * 64 + cc0 + i * 2 + 1];
          ast8(dst + i * 2, p.u);
        }
      }
      __syncthreads();
    }
  };

  // ---------- fc3: group-local, 2 rows per WG ----------
  auto fc3p = [&](int kidx) {
    float* GsF = (float*)Gs;
    const float* src = y2 + (size_t)(row0 + lb * 2) * 512;
    U8 v0, v1;
    v0.u = ald8(src + tid * 4);
    v1.u = ald8(src + tid * 4 + 2);
    *(ull*)&GsF[tid * 4] = v0.u;
    *(ull*)&GsF[tid * 4 + 2] = v1.u;
    __syncthreads();
    int rloc = w >> 1, o = w & 1;
    float s = 0.f;
    #pragma unroll
    for (int i = 0; i < 8; ++i) {
      int idx = l + i * 64;
      s += GsF[rloc * 512 + idx] * fc3_w[o * 512 + idx];
    }
    #pragma unroll
    for (int d = 32; d > 0; d >>= 1) s += __shfl_down(s, d, 64);
    if (l == 0)
      __hip_atomic_store(out + (size_t)(row0 + lb * 2 + rloc) * OSTR + kidx * 2 + o,
                         s + fc3_b[o], __ATOMIC_RELAXED, __HIP_MEMORY_SCOPE_AGENT);
    __syncthreads();
  };

  // ================= schedule (8 independent groups) =================
  for (int t = 0; t < 64; ++t) { fused(t > 0, true, t, false, 0); gbar(); }
  fused(true, false, 64, false, 0); gbar();   // L1(63)

  for (int kidx = 0; kidx < 17; ++kidx) {
    const us* h1cur = ((63 + kidx) & 1) ? hp1_1 : hp1_0;
    headg(h1cur, Wpf1, fc1_b, nullptr, y1p); gbar();
    headg(y1p, Wpf2, fc2_b, y2, nullptr); gbar();
    fc3p(kidx);
    if (kidx < 16) {
      gbar();
      fused(false, true, 64 + kidx, true, kidx); gbar();
      fused(true, false, 65 + kidx, false, 0); gbar();
    }
  }
}

} // namespace

extern "C" void kernel_launch(void* const* d_in, const int* in_sizes, int n_in,
                              void* d_out, int out_size, void* d_ws, size_t ws_size,
                              hipStream_t stream) {
  const float* x     = (const float*)d_in[0];
  const float* w_ih0 = (const float*)d_in[1];
  const float* w_hh0 = (const float*)d_in[2];
  const float* b_ih0 = (const float*)d_in[3];
  const float* b_hh0 = (const float*)d_in[4];
  const float* w_ih1 = (const float*)d_in[5];
  const float* w_hh1 = (const float*)d_in[6];
  const float* b_ih1 = (const float*)d_in[7];
  const float* b_hh1 = (const float*)d_in[8];
  const float* fc1_w = (const float*)d_in[9];
  const float* fc1_b = (const float*)d_in[10];
  const float* fc2_w = (const float*)d_in[11];
  const float* fc2_b = (const float*)d_in[12];
  const float* fc3_w = (const float*)d_in[13];
  const float* fc3_b = (const float*)d_in[14];
  float* out = (float*)d_out;
  char* wsb = (char*)d_ws;

  constexpr size_t MB = 1048576;
  constexpr size_t O_WP0  = 0;
  constexpr size_t O_WP1  = 4456448;
  constexpr size_t O_WPF1 = O_WP1 + 8388608;
  constexpr size_t O_WPF2 = O_WPF1 + MB;
  constexpr size_t O_BS0  = O_WPF2 + MB;
  constexpr size_t O_BS1  = O_BS0 + 8192;
  constexpr size_t O_CNT  = O_BS1 + 8192;
  constexpr size_t O_HP0B = O_CNT + 4096;           // hp0_1 (zeroed)
  constexpr size_t O_HP1B = O_HP0B + MB;            // hp1_1 (zeroed)
  constexpr size_t O_C0   = O_HP1B + MB;            // c0 (zeroed)
  constexpr size_t O_C1   = O_C0 + MB;              // c1 (zeroed)
  constexpr size_t O_HP0A = O_C1 + MB;
  constexpr size_t O_HP1A = O_HP0A + MB;
  constexpr size_t O_Y1P  = O_HP1A + MB;
  constexpr size_t O_Y2   = O_Y1P + MB;

  us* Wp0  = (us*)(wsb + O_WP0);
  us* Wp1  = (us*)(wsb + O_WP1);
  us* Wpf1 = (us*)(wsb + O_WPF1);
  us* Wpf2 = (us*)(wsb + O_WPF2);
  float* bs0 = (float*)(wsb + O_BS0);
  float* bs1 = (float*)(wsb + O_BS1);
  int* cnt   = (int*)(wsb + O_CNT);
  us* hp0_1 = (us*)(wsb + O_HP0B);
  us* hp1_1 = (us*)(wsb + O_HP1B);
  float* c0 = (float*)(wsb + O_C0);
  float* c1 = (float*)(wsb + O_C1);
  us* hp0_0 = (us*)(wsb + O_HP0A);
  us* hp1_0 = (us*)(wsb + O_HP1A);
  us* y1p   = (us*)(wsb + O_Y1P);
  float* y2 = (float*)(wsb + O_Y2);

  pack_w_kernel<<<dim3(32 * 17), 256, 0, stream>>>(w_ih0, w_hh0, 32, 512, 17, 0, Wp0);
  pack_w_kernel<<<dim3(32 * 32), 256, 0, stream>>>(w_ih1, w_hh1, 512, 512, 32, 0, Wp1);
  pack_w_kernel<<<dim3(8 * 16), 256, 0, stream>>>(fc1_w, fc1_w, 512, 512, 16, 1, Wpf1);
  pack_w_kernel<<<dim3(8 * 16), 256, 0, stream>>>(fc2_w, fc2_w, 512, 512, 16, 1, Wpf2);
  bsum_kernel<<<dim3(16), 256, 0, stream>>>(b_ih0, b_hh0, b_ih1, b_hh1, bs0, bs1);
  hipMemsetAsync(wsb + O_CNT, 0, 4096 + 4 * MB, stream);

  persist_kernel<<<dim3(256), dim3(256), 0, stream>>>(
      x, Wp0, Wp1, Wpf1, Wpf2, bs0, bs1, fc1_b, fc2_b, fc3_w, fc3_b,
      hp0_0, hp0_1, hp1_0, hp1_1, c0, c1, y1p, y2, out, cnt);
}

// Round 16
// 2509.358 us; speedup vs baseline: 1.1772x; 1.0088x over previous
//
#include <hip/hip_runtime.h>
#include <math.h>

typedef short s16x4 __attribute__((ext_vector_type(4)));
typedef short s16x8 __attribute__((ext_vector_type(8)));
typedef float f32x4 __attribute__((ext_vector_type(4)));
typedef unsigned short us;
typedef unsigned long long ull;

#define WAITVM(N) do { asm volatile("s_waitcnt vmcnt(" #N ")" ::: "memory"); __builtin_amdgcn_sched_barrier(0); } while (0)

namespace {
constexpr int T = 80, Fdim = 32, H = 512, OSTR = 34;

__device__ __forceinline__ us f2bf(float f) {
  union { float f; unsigned u; } x; x.f = f;
  unsigned u = x.u; u += 0x7fffu + ((u >> 16) & 1u);
  return (us)(u >> 16);
}
__device__ __forceinline__ float bf2f(us s) {
  union { unsigned u; float f; } x; x.u = ((unsigned)s) << 16; return x.f;
}
__device__ __forceinline__ float sigf(float v) { return 1.f / (1.f + expf(-v)); }
__device__ __forceinline__ float geluf(float v) {
  return 0.5f * v * (1.f + erff(v * 0.70710678118654752f));
}

__device__ __forceinline__ ull ald8(const void* p) {
  return __hip_atomic_load((const ull*)p, __ATOMIC_RELAXED, __HIP_MEMORY_SCOPE_AGENT);
}
__device__ __forceinline__ void ast8(void* p, ull v) {
  __hip_atomic_store((ull*)p, v, __ATOMIC_RELAXED, __HIP_MEMORY_SCOPE_AGENT);
}
__device__ __forceinline__ void ast4f(float* p, float v) {
  __hip_atomic_store(p, v, __ATOMIC_RELAXED, __HIP_MEMORY_SCOPE_AGENT);
}

union U8 { ull u; s16x4 v4; float f[2]; };
union S8 { s16x8 v; ull u[2]; };

struct SetA { ull a0, a1, a2, a3; };
struct SetB { s16x8 b10, b11, b00, b01; };
struct HSetA { ull a0, a1; };
struct HSetB { s16x8 b0h, b0l, b1h, b1l; };

// ---------------- weight pre-pack (unchanged) ----------------
__global__ __launch_bounds__(256)
void pack_w_kernel(const float* __restrict__ w1, const float* __restrict__ w2,
                   int K1, int K2, int NKC, int head, us* __restrict__ dst) {
  int bid = blockIdx.x;
  int jb = bid / NKC, kc = bid % NKC;
  int tid = threadIdx.x;
  int strip = tid >> 6, l = tid & 63;
  int nl = l & 15, kg = l >> 4;
  int n = head ? (jb * 64 + strip * 16 + nl) : (strip * 512 + jb * 16 + nl);
  s16x8 h8, l8;
  #pragma unroll
  for (int i = 0; i < 8; ++i) {
    int k = kc * 32 + kg * 8 + i;
    float v = (k < K1) ? w1[(size_t)n * K1 + k] : w2[(size_t)n * K2 + (k - K1)];
    us h = f2bf(v);
    h8[i] = (short)h;
    l8[i] = (short)f2bf(v - bf2f(h));
  }
  size_t base = (size_t)bid * 4096;
  *(s16x8*)&dst[base + (size_t)(strip * 2 + 0) * 512 + l * 8] = h8;
  *(s16x8*)&dst[base + (size_t)(strip * 2 + 1) * 512 + l * 8] = l8;
}

__global__ __launch_bounds__(256)
void bsum_kernel(const float* bi0, const float* bh0, const float* bi1, const float* bh1,
                 float* bs0, float* bs1) {
  int i = blockIdx.x * 256 + threadIdx.x;
  if (i < 2048) bs0[i] = bi0[i] + bh0[i];
  else { int j = i - 2048; bs1[j] = bi1[j] + bh1[j]; }
}

// ---------------- persistent whole-model kernel ----------------
// 256 WGs = 8 independent groups (64 batch rows) x 32 WGs (16 h-cols).
// B direct L2->reg; A through 8 LDS slots. Arrive/wait-split group barrier;
// fc3 fused into head2 epilogue via atomicAdd (out pre-initialized to bias).
__global__ __launch_bounds__(256, 1)
void persist_kernel(const float* __restrict__ x,
                    const us* __restrict__ Wp0, const us* __restrict__ Wp1,
                    const us* __restrict__ Wpf1, const us* __restrict__ Wpf2,
                    const float* __restrict__ bs0, const float* __restrict__ bs1,
                    const float* __restrict__ fc1_b, const float* __restrict__ fc2_b,
                    const float* __restrict__ fc3_w, const float* __restrict__ fc3_b,
                    us* hp0_0, us* hp0_1, us* hp1_0, us* hp1_1,
                    float* c0, float* c1, us* y1p,
                    float* out, int* cnt)
{
  __shared__ __align__(16) us Ash[8][4096];
  __shared__ __align__(16) float Gs[4][64][16];

  const int tid = threadIdx.x;
  const int bid = blockIdx.x;
  const int w = tid >> 6, l = tid & 63;
  const int m = bid >> 5;                      // group 0..7 (64 rows)
  const int lb = bid & 31;                     // group-local WG id
  const int jb = (lb & 7) * 4 + (lb >> 3);     // h-col slice 0..31
  const int row0 = m * 64;
  const int j0 = jb * 16;
  const int base31 = j0 & 31;

  const us* WpJ0 = Wp0 + (size_t)jb * 17 * 4096;
  const us* WpJ1 = Wp1 + (size_t)jb * 32 * 4096;

  int ph = 0;
  auto garrive = [&]() {
    ++ph;
    WAITVM(0);
    __syncthreads();
    if (tid == 0)
      __hip_atomic_fetch_add(&cnt[m * 64], 1, __ATOMIC_RELEASE,
                             __HIP_MEMORY_SCOPE_AGENT);
  };
  auto gwait = [&]() {
    if (tid == 0) {
      while (__hip_atomic_load(&cnt[m * 64], __ATOMIC_RELAXED,
                               __HIP_MEMORY_SCOPE_AGENT) < 32 * ph)
        __builtin_amdgcn_s_sleep(1);
      __builtin_amdgcn_fence(__ATOMIC_ACQUIRE, "workgroup");
    }
    __syncthreads();
  };

  // ---------- fused LSTM phase: {L1(t-1) if DO1} + {L0(t) if DO0} ----------
  // Performs its own gwait() AFTER issuing the first B-chunk loads (overlap).
  auto fused = [&](bool DO1, bool DO0, int t, bool use_fb, int kidx) {
    const us* h0prev = ((t + 1) & 1) ? hp0_1 : hp0_0;
    const us* h1prev = (t & 1) ? hp1_1 : hp1_0;
    us* h1w = ((t + 1) & 1) ? hp1_1 : hp1_0;
    us* h0w = (t & 1) ? hp0_1 : hp0_0;

    f32x4 acc0[4], acc1[4];
    #pragma unroll
    for (int mf = 0; mf < 4; ++mf) {
      acc0[mf] = {0.f, 0.f, 0.f, 0.f};
      acc1[mf] = {0.f, 0.f, 0.f, 0.f};
    }
    const int NP = DO1 ? 32 : 16;
    SetA A0s, A1s, A2s, A3s;
    SetB B0s, B1s, B2s, B3s;

    auto issA = [&](int c, SetA& R) {
      if (c >= NP) return;
      const us* a = ((c < 16) ? h0prev : h1prev) + (size_t)(m * 16 + (c & 15)) * 4096;
      R.a0 = ald8(a + tid * 8);
      R.a1 = ald8(a + tid * 8 + 4);
      R.a2 = ald8(a + 2048 + tid * 8);
      R.a3 = ald8(a + 2048 + tid * 8 + 4);
    };
    auto issB = [&](int c, SetB& R) {
      if (c >= NP) return;
      if (DO1) { const us* b = WpJ1 + (size_t)c * 4096 + w * 1024 + l * 8;
                 R.b10 = *(const s16x8*)(b);
                 R.b11 = *(const s16x8*)(b + 512); }
      if (DO0 && c < 16) { const us* b = WpJ0 + (size_t)(c + 1) * 4096 + w * 1024 + l * 8;
                 R.b00 = *(const s16x8*)(b);
                 R.b01 = *(const s16x8*)(b + 512); }
    };
    auto wrtA = [&](int c, SetA& R) {
      if (c >= NP) return;
      int sl = c & 7;
      *(ull*)&Ash[sl][tid * 8] = R.a0;
      *(ull*)&Ash[sl][tid * 8 + 4] = R.a1;
      *(ull*)&Ash[sl][2048 + tid * 8] = R.a2;
      *(ull*)&Ash[sl][2048 + tid * 8 + 4] = R.a3;
    };
    auto lcomp = [&](int kc, SetB& B, bool c1on, bool c0on) {
      int sl = kc & 7;
      #pragma unroll
      for (int mf = 0; mf < 4; ++mf) {
        s16x8 Ah = *(const s16x8*)&Ash[sl][(mf * 2 + 0) * 512 + l * 8];
        s16x8 Al = *(const s16x8*)&Ash[sl][(mf * 2 + 1) * 512 + l * 8];
        if (c1on) {
          acc1[mf] = __builtin_amdgcn_mfma_f32_16x16x32_bf16(Ah, B.b10, acc1[mf], 0, 0, 0);
          acc1[mf] = __builtin_amdgcn_mfma_f32_16x16x32_bf16(Ah, B.b11, acc1[mf], 0, 0, 0);
          acc1[mf] = __builtin_amdgcn_mfma_f32_16x16x32_bf16(Al, B.b10, acc1[mf], 0, 0, 0);
        }
        if (c0on) {
          acc0[mf] = __builtin_amdgcn_mfma_f32_16x16x32_bf16(Ah, B.b00, acc0[mf], 0, 0, 0);
          acc0[mf] = __builtin_amdgcn_mfma_f32_16x16x32_bf16(Ah, B.b01, acc0[mf], 0, 0, 0);
          acc0[mf] = __builtin_amdgcn_mfma_f32_16x16x32_bf16(Al, B.b00, acc0[mf], 0, 0, 0);
        }
      }
    };

    // B loads first (no cross-WG dependency) -> overlap barrier wait
    issB(0, B0s); issB(1, B1s); issB(2, B2s); issB(3, B3s);
    gwait();
    // A prologue: chunks 0..3 staged+written, 4..7 in flight
    issA(0, A0s); issA(1, A1s); issA(2, A2s); issA(3, A3s);
    wrtA(0, A0s); wrtA(1, A1s); wrtA(2, A2s); wrtA(3, A3s);
    issA(4, A0s); issA(5, A1s); issA(6, A2s); issA(7, A3s);
    __syncthreads();
    // steady state: per 4-chunk block, 2 barriers
    for (int base = 0; base < NP; base += 4) {
      { int kc = base + 0; lcomp(kc, B0s, DO1, DO0 && kc < 16); issB(kc + 4, B0s); }
      { int kc = base + 1; lcomp(kc, B1s, DO1, DO0 && kc < 16); issB(kc + 4, B1s); }
      { int kc = base + 2; lcomp(kc, B2s, DO1, DO0 && kc < 16); issB(kc + 4, B2s); }
      { int kc = base + 3; lcomp(kc, B3s, DO1, DO0 && kc < 16); issB(kc + 4, B3s); }
      __syncthreads();
      wrtA(base + 4, A0s); wrtA(base + 5, A1s);
      wrtA(base + 6, A2s); wrtA(base + 7, A3s);
      issA(base + 8, A0s); issA(base + 9, A1s);
      issA(base + 10, A2s); issA(base + 11, A3s);
      __syncthreads();
    }

    if (DO0) {  // x chunk (L0 weight chunk 0), B direct from L2
      SetB Bx;
      { const us* b = WpJ0 + w * 1024 + l * 8;
        Bx.b00 = *(const s16x8*)(b);
        Bx.b01 = *(const s16x8*)(b + 512); }
      int srow = tid >> 2, skg = tid & 3;
      const float* xp = x + (size_t)(row0 + srow) * (T * Fdim) + (size_t)t * Fdim + skg * 8;
      float v[8];
      #pragma unroll
      for (int i = 0; i < 8; ++i) v[i] = xp[i];
      if (use_fb && skg == 0) {
        const float* op = out + (size_t)(row0 + srow) * OSTR + kidx * 2;
        v[4] = __hip_atomic_load(op, __ATOMIC_RELAXED, __HIP_MEMORY_SCOPE_AGENT);
        v[5] = __hip_atomic_load(op + 1, __ATOMIC_RELAXED, __HIP_MEMORY_SCOPE_AGENT);
      }
      s16x8 h8, l8;
      #pragma unroll
      for (int i = 0; i < 8; ++i) {
        us hh = f2bf(v[i]);
        h8[i] = (short)hh;
        l8[i] = (short)f2bf(v[i] - bf2f(hh));
      }
      int slane = skg * 16 + (srow & 15), smf = srow >> 4;
      *(s16x8*)&Ash[0][(smf * 2 + 0) * 512 + slane * 8] = h8;
      *(s16x8*)&Ash[0][(smf * 2 + 1) * 512 + slane * 8] = l8;
      __syncthreads();
      lcomp(0, Bx, false, true);
    }

    // epilogue: stash gates -> cell -> packed coherent h write
    auto epi = [&](f32x4* acc, const float* bsum, float* cst, us* hw) {
      __syncthreads();
      float bsv = bsum[w * 512 + j0 + (l & 15)];
      #pragma unroll
      for (int mf = 0; mf < 4; ++mf)
        #pragma unroll
        for (int r = 0; r < 4; ++r)
          Gs[w][mf * 16 + (l >> 4) * 4 + r][l & 15] = acc[mf][r] + bsv;
      __syncthreads();
      int r = tid >> 2, sub = tid & 3, cc0 = sub * 4;
      float gvi[4], gvf[4], gvg[4], gvo[4], cv[4], cn[4], hv[4];
      #pragma unroll
      for (int q = 0; q < 4; ++q) {
        gvi[q] = Gs[0][r][cc0 + q]; gvf[q] = Gs[1][r][cc0 + q];
        gvg[q] = Gs[2][r][cc0 + q]; gvo[q] = Gs[3][r][cc0 + q];
      }
      size_t cix = (size_t)(row0 + r) * H + j0 + cc0;
      float4 cold = *(const float4*)&cst[cix];
      cv[0] = cold.x; cv[1] = cold.y; cv[2] = cold.z; cv[3] = cold.w;
      #pragma unroll
      for (int q = 0; q < 4; ++q) {
        float c2 = sigf(gvf[q]) * cv[q] + sigf(gvi[q]) * tanhf(gvg[q]);
        cn[q] = c2;
        hv[q] = sigf(gvo[q]) * tanhf(c2);
      }
      *(float4*)&cst[cix] = make_float4(cn[0], cn[1], cn[2], cn[3]);
      int kk = base31 + cc0;
      int kg = kk >> 3, i0 = kk & 7;
      int mf = r >> 4;
      int lane2 = kg * 16 + (r & 15);
      us* bb = hw + (size_t)(m * 16 + (j0 >> 5)) * 4096;
      U8 hh, hl;
      #pragma unroll
      for (int q = 0; q < 4; ++q) {
        us h2 = f2bf(hv[q]);
        hh.v4[q] = (short)h2;
        hl.v4[q] = (short)f2bf(hv[q] - bf2f(h2));
      }
      ast8(bb + (size_t)(mf * 2 + 0) * 512 + lane2 * 8 + i0, hh.u);
      ast8(bb + (size_t)(mf * 2 + 1) * 512 + lane2 * 8 + i0, hl.u);
      __syncthreads();
    };
    if (DO1) epi(acc1, bs1, c1, h1w);
    if (DO0) epi(acc0, bs0, c0, h0w);
  };

  // ---------- head GEMM: group-local, 16 of 32 WGs, 32 rows x 64 cols ----------
  // yp != null: head1 (pack y1). yp == null: head2 + fused fc3 (atomicAdd to out).
  auto headg = [&](const us* apack, const us* Wp, const float* bias,
                   us* yp, int kidx) {
    if (lb < 16) {
      const int mhl = lb >> 3, cb = lb & 7;
      const int hrow0 = row0 + mhl * 32, hj0 = cb * 64;
      const int wm = w >> 1, wn = w & 1;
      f32x4 hacc[2];
      hacc[0] = {0.f, 0.f, 0.f, 0.f};
      hacc[1] = {0.f, 0.f, 0.f, 0.f};
      HSetA HA0, HA1, HA2, HA3;
      HSetB HB0, HB1;
      auto hissA = [&](int c, HSetA& R) {
        if (c >= 16) return;
        const us* a = apack + (size_t)(m * 16 + c) * 4096 + mhl * 2048;
        R.a0 = ald8(a + tid * 8);
        R.a1 = ald8(a + tid * 8 + 4);
      };
      auto hissB = [&](int c, HSetB& R) {
        if (c >= 16) return;
        const us* b = Wp + (size_t)(cb * 16 + c) * 4096 + wn * 2048 + l * 8;
        R.b0h = *(const s16x8*)(b);
        R.b0l = *(const s16x8*)(b + 512);
        R.b1h = *(const s16x8*)(b + 1024);
        R.b1l = *(const s16x8*)(b + 1536);
      };
      auto hwrtA = [&](int c, HSetA& R) {
        if (c >= 16) return;
        int sl = c % 3;
        *(ull*)&Ash[sl][tid * 8] = R.a0;
        *(ull*)&Ash[sl][tid * 8 + 4] = R.a1;
      };
      auto hcmp = [&](int sl, HSetB& B) {
        s16x8 Ah = *(const s16x8*)&Ash[sl][(wm * 2 + 0) * 512 + l * 8];
        s16x8 Al = *(const s16x8*)&Ash[sl][(wm * 2 + 1) * 512 + l * 8];
        hacc[0] = __builtin_amdgcn_mfma_f32_16x16x32_bf16(Ah, B.b0h, hacc[0], 0, 0, 0);
        hacc[0] = __builtin_amdgcn_mfma_f32_16x16x32_bf16(Ah, B.b0l, hacc[0], 0, 0, 0);
        hacc[0] = __builtin_amdgcn_mfma_f32_16x16x32_bf16(Al, B.b0h, hacc[0], 0, 0, 0);
        hacc[1] = __builtin_amdgcn_mfma_f32_16x16x32_bf16(Ah, B.b1h, hacc[1], 0, 0, 0);
        hacc[1] = __builtin_amdgcn_mfma_f32_16x16x32_bf16(Ah, B.b1l, hacc[1], 0, 0, 0);
        hacc[1] = __builtin_amdgcn_mfma_f32_16x16x32_bf16(Al, B.b1h, hacc[1], 0, 0, 0);
      };
      hissA(0, HA0); hissA(1, HA1); hissA(2, HA2); hissA(3, HA3);
      hwrtA(0, HA0); hissA(4, HA0);
      hwrtA(1, HA1); hissA(5, HA1);
      hissB(0, HB0); hissB(1, HB1);
      __syncthreads();
      for (int base = 0; base < 16; base += 4) {
        { int kc = base + 0; hcmp(kc % 3, HB0); hissB(kc + 2, HB0);
          hwrtA(kc + 2, HA2); hissA(kc + 6, HA2); __syncthreads(); }
        { int kc = base + 1; hcmp(kc % 3, HB1); hissB(kc + 2, HB1);
          hwrtA(kc + 2, HA3); hissA(kc + 6, HA3); __syncthreads(); }
        { int kc = base + 2; hcmp(kc % 3, HB0); hissB(kc + 2, HB0);
          hwrtA(kc + 2, HA0); hissA(kc + 6, HA0); __syncthreads(); }
        { int kc = base + 3; hcmp(kc % 3, HB1); hissB(kc + 2, HB1);
          hwrtA(kc + 2, HA1); hissA(kc + 6, HA1); __syncthreads(); }
      }
      __syncthreads();
      float* GsF = (float*)Gs;
      #pragma unroll
      for (int nf = 0; nf < 2; ++nf)
        #pragma unroll
        for (int rq = 0; rq < 4; ++rq) {
          int rr = wm * 16 + (l >> 4) * 4 + rq;
          int ccl = wn * 32 + nf * 16 + (l & 15);
          GsF[rr * 64 + ccl] = geluf(hacc[nf][rq] + bias[hj0 + ccl]);
        }
      __syncthreads();
      if (yp) {
        // head1: packed bf16 hi/lo fragment layout (consumable as next A)
        int chunk = tid >> 7, tt = tid & 127;
        int mf_loc = tt >> 6, lane = tt & 63;
        int row = mf_loc * 16 + (lane & 15);
        int kg = lane >> 4;
        S8 hi, lo;
        #pragma unroll
        for (int i = 0; i < 8; ++i) {
          float v = GsF[row * 64 + chunk * 32 + kg * 8 + i];
          us hh = f2bf(v);
          hi.v[i] = (short)hh;
          lo.v[i] = (short)f2bf(v - bf2f(hh));
        }
        us* dst = yp + ((size_t)m * 16 + (cb * 2 + chunk)) * 4096 + mhl * 2048;
        ast8(dst + (size_t)(mf_loc * 2 + 0) * 512 + lane * 8, hi.u[0]);
        ast8(dst + (size_t)(mf_loc * 2 + 0) * 512 + lane * 8 + 4, hi.u[1]);
        ast8(dst + (size_t)(mf_loc * 2 + 1) * 512 + lane * 8, lo.u[0]);
        ast8(dst + (size_t)(mf_loc * 2 + 1) * 512 + lane * 8 + 4, lo.u[1]);
      } else {
        // head2 + fc3: partial dot over this WG's 64 cols, atomicAdd into out
        int r = tid >> 3, cg = tid & 7;
        float p0 = 0.f, p1 = 0.f;
        #pragma unroll
        for (int i = 0; i < 8; ++i) {
          float yv = GsF[r * 64 + cg * 8 + i];
          int col = hj0 + cg * 8 + i;
          p0 += yv * fc3_w[col];
          p1 += yv * fc3_w[512 + col];
        }
        #pragma unroll
        for (int d = 4; d > 0; d >>= 1) {
          p0 += __shfl_down(p0, d, 8);
          p1 += __shfl_down(p1, d, 8);
        }
        if (cg == 0) {
          atomicAdd(out + (size_t)(hrow0 + r) * OSTR + kidx * 2, p0);
          atomicAdd(out + (size_t)(hrow0 + r) * OSTR + kidx * 2 + 1, p1);
        }
      }
      __syncthreads();
    }
  };

  auto h1buf = [&](int t) { return (t & 1) ? hp1_1 : hp1_0; };

  // ================= schedule (8 independent groups) =================
  // uniform phase protocol: gwait -> work -> garrive (fused gwaits internally)
  for (int t = 0; t < 64; ++t) { fused(t > 0, true, t, false, 0); garrive(); }
  fused(true, false, 64, false, 0); garrive();   // L1(63)

  for (int kidx = 0; kidx < 17; ++kidx) {
    const us* h1cur = h1buf(63 + kidx);
    // head1 phase (+ out-slot init to bias by idle WG lb==16)
    gwait();
    headg(h1cur, Wpf1, fc1_b, y1p, kidx);
    if (lb == 16 && tid < 128) {
      int r2 = tid >> 1, o = tid & 1;
      ast4f(out + (size_t)(row0 + r2) * OSTR + kidx * 2 + o, fc3_b[o]);
    }
    garrive();
    // head2 + fc3 phase
    gwait();
    headg(y1p, Wpf2, fc2_b, nullptr, kidx);
    garrive();
    if (kidx < 16) {
      fused(false, true, 64 + kidx, true, kidx); garrive();
      fused(true, false, 65 + kidx, false, 0); garrive();
    }
  }
}

} // namespace

extern "C" void kernel_launch(void* const* d_in, const int* in_sizes, int n_in,
                              void* d_out, int out_size, void* d_ws, size_t ws_size,
                              hipStream_t stream) {
  const float* x     = (const float*)d_in[0];
  const float* w_ih0 = (const float*)d_in[1];
  const float* w_hh0 = (const float*)d_in[2];
  const float* b_ih0 = (const float*)d_in[3];
  const float* b_hh0 = (const float*)d_in[4];
  const float* w_ih1 = (const float*)d_in[5];
  const float* w_hh1 = (const float*)d_in[6];
  const float* b_ih1 = (const float*)d_in[7];
  const float* b_hh1 = (const float*)d_in[8];
  const float* fc1_w = (const float*)d_in[9];
  const float* fc1_b = (const float*)d_in[10];
  const float* fc2_w = (const float*)d_in[11];
  const float* fc2_b = (const float*)d_in[12];
  const float* fc3_w = (const float*)d_in[13];
  const float* fc3_b = (const float*)d_in[14];
  float* out = (float*)d_out;
  char* wsb = (char*)d_ws;

  constexpr size_t MB = 1048576;
  constexpr size_t O_WP0  = 0;
  constexpr size_t O_WP1  = 4456448;
  constexpr size_t O_WPF1 = O_WP1 + 8388608;
  constexpr size_t O_WPF2 = O_WPF1 + MB;
  constexpr size_t O_BS0  = O_WPF2 + MB;
  constexpr size_t O_BS1  = O_BS0 + 8192;
  constexpr size_t O_CNT  = O_BS1 + 8192;
  constexpr size_t O_HP0B = O_CNT + 4096;           // hp0_1 (zeroed)
  constexpr size_t O_HP1B = O_HP0B + MB;            // hp1_1 (zeroed)
  constexpr size_t O_C0   = O_HP1B + MB;            // c0 (zeroed)
  constexpr size_t O_C1   = O_C0 + MB;              // c1 (zeroed)
  constexpr size_t O_HP0A = O_C1 + MB;
  constexpr size_t O_HP1A = O_HP0A + MB;
  constexpr size_t O_Y1P  = O_HP1A + MB;

  us* Wp0  = (us*)(wsb + O_WP0);
  us* Wp1  = (us*)(wsb + O_WP1);
  us* Wpf1 = (us*)(wsb + O_WPF1);
  us* Wpf2 = (us*)(wsb + O_WPF2);
  float* bs0 = (float*)(wsb + O_BS0);
  float* bs1 = (float*)(wsb + O_BS1);
  int* cnt   = (int*)(wsb + O_CNT);
  us* hp0_1 = (us*)(wsb + O_HP0B);
  us* hp1_1 = (us*)(wsb + O_HP1B);
  float* c0 = (float*)(wsb + O_C0);
  float* c1 = (float*)(wsb + O_C1);
  us* hp0_0 = (us*)(wsb + O_HP0A);
  us* hp1_0 = (us*)(wsb + O_HP1A);
  us* y1p   = (us*)(wsb + O_Y1P);

  pack_w_kernel<<<dim3(32 * 17), 256, 0, stream>>>(w_ih0, w_hh0, 32, 512, 17, 0, Wp0);
  pack_w_kernel<<<dim3(32 * 32), 256, 0, stream>>>(w_ih1, w_hh1, 512, 512, 32, 0, Wp1);
  pack_w_kernel<<<dim3(8 * 16), 256, 0, stream>>>(fc1_w, fc1_w, 512, 512, 16, 1, Wpf1);
  pack_w_kernel<<<dim3(8 * 16), 256, 0, stream>>>(fc2_w, fc2_w, 512, 512, 16, 1, Wpf2);
  bsum_kernel<<<dim3(16), 256, 0, stream>>>(b_ih0, b_hh0, b_ih1, b_hh1, bs0, bs1);
  hipMemsetAsync(wsb + O_CNT, 0, 4096 + 4 * MB, stream);

  persist_kernel<<<dim3(256), dim3(256), 0, stream>>>(
      x, Wp0, Wp1, Wpf1, Wpf2, bs0, bs1, fc1_b, fc2_b, fc3_w, fc3_b,
      hp0_0, hp0_1, hp1_0, hp1_1, c0, c1, y1p, out, cnt);
}

// Round 17
// 2377.766 us; speedup vs baseline: 1.2424x; 1.0553x over previous
//
#include <hip/hip_runtime.h>
#include <math.h>

typedef short s16x4 __attribute__((ext_vector_type(4)));
typedef short s16x8 __attribute__((ext_vector_type(8)));
typedef float f32x4 __attribute__((ext_vector_type(4)));
typedef unsigned short us;
typedef unsigned long long ull;

#define WAITVM(N) do { asm volatile("s_waitcnt vmcnt(" #N ")" ::: "memory"); __builtin_amdgcn_sched_barrier(0); } while (0)

namespace {
constexpr int T = 80, Fdim = 32, H = 512, OSTR = 34;

__device__ __forceinline__ us f2bf(float f) {
  union { float f; unsigned u; } x; x.f = f;
  unsigned u = x.u; u += 0x7fffu + ((u >> 16) & 1u);
  return (us)(u >> 16);
}
__device__ __forceinline__ float bf2f(us s) {
  union { unsigned u; float f; } x; x.u = ((unsigned)s) << 16; return x.f;
}
__device__ __forceinline__ float sigf(float v) { return 1.f / (1.f + expf(-v)); }
__device__ __forceinline__ float geluf(float v) {
  return 0.5f * v * (1.f + erff(v * 0.70710678118654752f));
}

__device__ __forceinline__ ull ald8(const void* p) {
  return __hip_atomic_load((const ull*)p, __ATOMIC_RELAXED, __HIP_MEMORY_SCOPE_AGENT);
}
__device__ __forceinline__ void ast8(void* p, ull v) {
  __hip_atomic_store((ull*)p, v, __ATOMIC_RELAXED, __HIP_MEMORY_SCOPE_AGENT);
}
__device__ __forceinline__ void ast4f(float* p, float v) {
  __hip_atomic_store(p, v, __ATOMIC_RELAXED, __HIP_MEMORY_SCOPE_AGENT);
}

union U8 { ull u; s16x4 v4; float f[2]; };
union S8 { s16x8 v; ull u[2]; };

struct SetA { ull a0, a1, a2, a3; };
struct SetB { s16x8 b10, b11, b00, b01; };
struct HSetA { ull a0, a1; };
struct HSetB { s16x8 b0h, b0l, b1h, b1l; };

// ---------------- weight pre-pack (unchanged) ----------------
__global__ __launch_bounds__(256)
void pack_w_kernel(const float* __restrict__ w1, const float* __restrict__ w2,
                   int K1, int K2, int NKC, int head, us* __restrict__ dst) {
  int bid = blockIdx.x;
  int jb = bid / NKC, kc = bid % NKC;
  int tid = threadIdx.x;
  int strip = tid >> 6, l = tid & 63;
  int nl = l & 15, kg = l >> 4;
  int n = head ? (jb * 64 + strip * 16 + nl) : (strip * 512 + jb * 16 + nl);
  s16x8 h8, l8;
  #pragma unroll
  for (int i = 0; i < 8; ++i) {
    int k = kc * 32 + kg * 8 + i;
    float v = (k < K1) ? w1[(size_t)n * K1 + k] : w2[(size_t)n * K2 + (k - K1)];
    us h = f2bf(v);
    h8[i] = (short)h;
    l8[i] = (short)f2bf(v - bf2f(h));
  }
  size_t base = (size_t)bid * 4096;
  *(s16x8*)&dst[base + (size_t)(strip * 2 + 0) * 512 + l * 8] = h8;
  *(s16x8*)&dst[base + (size_t)(strip * 2 + 1) * 512 + l * 8] = l8;
}

__global__ __launch_bounds__(256)
void bsum_kernel(const float* bi0, const float* bh0, const float* bi1, const float* bh1,
                 float* bs0, float* bs1) {
  int i = blockIdx.x * 256 + threadIdx.x;
  if (i < 2048) bs0[i] = bi0[i] + bh0[i];
  else { int j = i - 2048; bs1[j] = bi1[j] + bh1[j]; }
}

// ---------------- persistent whole-model kernel ----------------
// 256 WGs = 8 groups (64 rows) x 32 WGs (16 h-cols). Flag-array group barrier
// (parallel stores + parallel polls). AR fused phases compute visibility-safe
// K-chunks BEFORE the barrier wait (overlap with previous phase tail).
__global__ __launch_bounds__(256, 1)
void persist_kernel(const float* __restrict__ x,
                    const us* __restrict__ Wp0, const us* __restrict__ Wp1,
                    const us* __restrict__ Wpf1, const us* __restrict__ Wpf2,
                    const float* __restrict__ bs0, const float* __restrict__ bs1,
                    const float* __restrict__ fc1_b, const float* __restrict__ fc2_b,
                    const float* __restrict__ fc3_w, const float* __restrict__ fc3_b,
                    us* hp0_0, us* hp0_1, us* hp1_0, us* hp1_1,
                    float* c0, float* c1, us* y1p,
                    float* out, int* cnt)
{
  __shared__ __align__(16) us Ash[8][4096];
  __shared__ __align__(16) float Gs[4][64][16];

  const int tid = threadIdx.x;
  const int bid = blockIdx.x;
  const int w = tid >> 6, l = tid & 63;
  const int m = bid >> 5;                      // group 0..7 (64 rows)
  const int lb = bid & 31;                     // group-local WG id
  const int jb = (lb & 7) * 4 + (lb >> 3);     // h-col slice 0..31
  const int row0 = m * 64;
  const int j0 = jb * 16;
  const int base31 = j0 & 31;

  const us* WpJ0 = Wp0 + (size_t)jb * 17 * 4096;
  const us* WpJ1 = Wp1 + (size_t)jb * 32 * 4096;

  int ph = 0;
  // flag-array barrier: 32 parallel flag stores / 32 parallel polls per group
  auto garrive = [&]() {
    ++ph;
    WAITVM(0);
    __syncthreads();
    if (tid == 0)
      __hip_atomic_store(&cnt[m * 512 + lb * 16], ph, __ATOMIC_RELEASE,
                         __HIP_MEMORY_SCOPE_AGENT);
  };
  auto gwait = [&]() {
    if (tid < 32) {
      while (__hip_atomic_load(&cnt[m * 512 + tid * 16], __ATOMIC_RELAXED,
                               __HIP_MEMORY_SCOPE_AGENT) < ph)
        __builtin_amdgcn_s_sleep(1);
      __builtin_amdgcn_fence(__ATOMIC_ACQUIRE, "workgroup");
    }
    __syncthreads();
  };

  // ---------- fused LSTM phase: {L1(t-1) if DO1} + {L0(t) if DO0} ----------
  // preh: h-chunk segment is visibility-safe pre-barrier (AR phases + t=0).
  // Calls gwait() internally exactly once.
  auto fused = [&](bool DO1, bool DO0, int t, bool use_fb, int kidx, bool preh) {
    const us* h0prev = ((t + 1) & 1) ? hp0_1 : hp0_0;
    const us* h1prev = (t & 1) ? hp1_1 : hp1_0;
    us* h1w = ((t + 1) & 1) ? hp1_1 : hp1_0;
    us* h0w = (t & 1) ? hp0_1 : hp0_0;

    f32x4 acc0[4], acc1[4];
    #pragma unroll
    for (int mf = 0; mf < 4; ++mf) {
      acc0[mf] = {0.f, 0.f, 0.f, 0.f};
      acc1[mf] = {0.f, 0.f, 0.f, 0.f};
    }
    const int NP = DO1 ? 32 : 16;
    SetA A0s, A1s, A2s, A3s;
    SetB B0s, B1s, B2s, B3s;

    auto issA = [&](int c, SetA& R, int hi) {
      if (c >= hi) return;
      const us* a = ((c < 16) ? h0prev : h1prev) + (size_t)(m * 16 + (c & 15)) * 4096;
      R.a0 = ald8(a + tid * 8);
      R.a1 = ald8(a + tid * 8 + 4);
      R.a2 = ald8(a + 2048 + tid * 8);
      R.a3 = ald8(a + 2048 + tid * 8 + 4);
    };
    auto issB = [&](int c, SetB& R, int hi) {
      if (c >= hi) return;
      if (DO1) { const us* b = WpJ1 + (size_t)c * 4096 + w * 1024 + l * 8;
                 R.b10 = *(const s16x8*)(b);
                 R.b11 = *(const s16x8*)(b + 512); }
      if (DO0 && c < 16) { const us* b = WpJ0 + (size_t)(c + 1) * 4096 + w * 1024 + l * 8;
                 R.b00 = *(const s16x8*)(b);
                 R.b01 = *(const s16x8*)(b + 512); }
    };
    auto wrtA = [&](int c, SetA& R, int hi) {
      if (c >= hi) return;
      int sl = c & 7;
      *(ull*)&Ash[sl][tid * 8] = R.a0;
      *(ull*)&Ash[sl][tid * 8 + 4] = R.a1;
      *(ull*)&Ash[sl][2048 + tid * 8] = R.a2;
      *(ull*)&Ash[sl][2048 + tid * 8 + 4] = R.a3;
    };
    auto lcomp = [&](int kc, SetB& B, bool c1on, bool c0on) {
      int sl = kc & 7;
      #pragma unroll
      for (int mf = 0; mf < 4; ++mf) {
        s16x8 Ah = *(const s16x8*)&Ash[sl][(mf * 2 + 0) * 512 + l * 8];
        s16x8 Al = *(const s16x8*)&Ash[sl][(mf * 2 + 1) * 512 + l * 8];
        if (c1on) {
          acc1[mf] = __builtin_amdgcn_mfma_f32_16x16x32_bf16(Ah, B.b10, acc1[mf], 0, 0, 0);
          acc1[mf] = __builtin_amdgcn_mfma_f32_16x16x32_bf16(Ah, B.b11, acc1[mf], 0, 0, 0);
          acc1[mf] = __builtin_amdgcn_mfma_f32_16x16x32_bf16(Al, B.b10, acc1[mf], 0, 0, 0);
        }
        if (c0on) {
          acc0[mf] = __builtin_amdgcn_mfma_f32_16x16x32_bf16(Ah, B.b00, acc0[mf], 0, 0, 0);
          acc0[mf] = __builtin_amdgcn_mfma_f32_16x16x32_bf16(Ah, B.b01, acc0[mf], 0, 0, 0);
          acc0[mf] = __builtin_amdgcn_mfma_f32_16x16x32_bf16(Al, B.b00, acc0[mf], 0, 0, 0);
        }
      }
    };

    // staged loop over chunk range [lo,hi); expects B sets preloaded with lo..lo+3
    auto runseg = [&](int lo, int hi) {
      issA(lo + 0, A0s, hi); issA(lo + 1, A1s, hi);
      issA(lo + 2, A2s, hi); issA(lo + 3, A3s, hi);
      wrtA(lo + 0, A0s, hi); wrtA(lo + 1, A1s, hi);
      wrtA(lo + 2, A2s, hi); wrtA(lo + 3, A3s, hi);
      issA(lo + 4, A0s, hi); issA(lo + 5, A1s, hi);
      issA(lo + 6, A2s, hi); issA(lo + 7, A3s, hi);
      __syncthreads();
      for (int base = lo; base < hi; base += 4) {
        { int kc = base + 0; lcomp(kc, B0s, DO1, DO0 && kc < 16); issB(kc + 4, B0s, hi); }
        { int kc = base + 1; lcomp(kc, B1s, DO1, DO0 && kc < 16); issB(kc + 4, B1s, hi); }
        { int kc = base + 2; lcomp(kc, B2s, DO1, DO0 && kc < 16); issB(kc + 4, B2s, hi); }
        { int kc = base + 3; lcomp(kc, B3s, DO1, DO0 && kc < 16); issB(kc + 4, B3s, hi); }
        __syncthreads();
        wrtA(base + 4, A0s, hi); wrtA(base + 5, A1s, hi);
        wrtA(base + 6, A2s, hi); wrtA(base + 7, A3s, hi);
        issA(base + 8, A0s, hi); issA(base + 9, A1s, hi);
        issA(base + 10, A2s, hi); issA(base + 11, A3s, hi);
        __syncthreads();
      }
    };

    if (preh) {
      if (DO1) {
        // AR L1: chunks 16..31 (h1, >=4 phases old) pre-barrier
        issB(16, B0s, 32); issB(17, B1s, 32); issB(18, B2s, 32); issB(19, B3s, 32);
        runseg(16, 32);
        issB(0, B0s, 16); issB(1, B1s, 16); issB(2, B2s, 16); issB(3, B3s, 16);
        gwait();
        runseg(0, 16);
      } else {
        // AR L0 (or t=0): chunks 0..15 (h0, >=4 phases old / zeros) pre-barrier
        issB(0, B0s, 16); issB(1, B1s, 16); issB(2, B2s, 16); issB(3, B3s, 16);
        runseg(0, 16);
        gwait();
      }
    } else {
      issB(0, B0s, NP); issB(1, B1s, NP); issB(2, B2s, NP); issB(3, B3s, NP);
      gwait();
      runseg(0, NP);
    }

    if (DO0) {  // x chunk (L0 weight chunk 0) — post-barrier (feedback)
      SetB Bx;
      { const us* b = WpJ0 + w * 1024 + l * 8;
        Bx.b00 = *(const s16x8*)(b);
        Bx.b01 = *(const s16x8*)(b + 512); }
      int srow = tid >> 2, skg = tid & 3;
      const float* xp = x + (size_t)(row0 + srow) * (T * Fdim) + (size_t)t * Fdim + skg * 8;
      float v[8];
      #pragma unroll
      for (int i = 0; i < 8; ++i) v[i] = xp[i];
      if (use_fb && skg == 0) {
        const float* op = out + (size_t)(row0 + srow) * OSTR + kidx * 2;
        v[4] = __hip_atomic_load(op, __ATOMIC_RELAXED, __HIP_MEMORY_SCOPE_AGENT);
        v[5] = __hip_atomic_load(op + 1, __ATOMIC_RELAXED, __HIP_MEMORY_SCOPE_AGENT);
      }
      s16x8 h8, l8;
      #pragma unroll
      for (int i = 0; i < 8; ++i) {
        us hh = f2bf(v[i]);
        h8[i] = (short)hh;
        l8[i] = (short)f2bf(v[i] - bf2f(hh));
      }
      int slane = skg * 16 + (srow & 15), smf = srow >> 4;
      *(s16x8*)&Ash[0][(smf * 2 + 0) * 512 + slane * 8] = h8;
      *(s16x8*)&Ash[0][(smf * 2 + 1) * 512 + slane * 8] = l8;
      __syncthreads();
      lcomp(0, Bx, false, true);
    }

    // epilogue: stash gates -> cell -> packed coherent h write
    auto epi = [&](f32x4* acc, const float* bsum, float* cst, us* hw) {
      __syncthreads();
      float bsv = bsum[w * 512 + j0 + (l & 15)];
      #pragma unroll
      for (int mf = 0; mf < 4; ++mf)
        #pragma unroll
        for (int r = 0; r < 4; ++r)
          Gs[w][mf * 16 + (l >> 4) * 4 + r][l & 15] = acc[mf][r] + bsv;
      __syncthreads();
      int r = tid >> 2, sub = tid & 3, cc0 = sub * 4;
      float gvi[4], gvf[4], gvg[4], gvo[4], cv[4], cn[4], hv[4];
      #pragma unroll
      for (int q = 0; q < 4; ++q) {
        gvi[q] = Gs[0][r][cc0 + q]; gvf[q] = Gs[1][r][cc0 + q];
        gvg[q] = Gs[2][r][cc0 + q]; gvo[q] = Gs[3][r][cc0 + q];
      }
      size_t cix = (size_t)(row0 + r) * H + j0 + cc0;
      float4 cold = *(const float4*)&cst[cix];
      cv[0] = cold.x; cv[1] = cold.y; cv[2] = cold.z; cv[3] = cold.w;
      #pragma unroll
      for (int q = 0; q < 4; ++q) {
        float c2 = sigf(gvf[q]) * cv[q] + sigf(gvi[q]) * tanhf(gvg[q]);
        cn[q] = c2;
        hv[q] = sigf(gvo[q]) * tanhf(c2);
      }
      *(float4*)&cst[cix] = make_float4(cn[0], cn[1], cn[2], cn[3]);
      int kk = base31 + cc0;
      int kg = kk >> 3, i0 = kk & 7;
      int mf = r >> 4;
      int lane2 = kg * 16 + (r & 15);
      us* bb = hw + (size_t)(m * 16 + (j0 >> 5)) * 4096;
      U8 hh, hl;
      #pragma unroll
      for (int q = 0; q < 4; ++q) {
        us h2 = f2bf(hv[q]);
        hh.v4[q] = (short)h2;
        hl.v4[q] = (short)f2bf(hv[q] - bf2f(h2));
      }
      ast8(bb + (size_t)(mf * 2 + 0) * 512 + lane2 * 8 + i0, hh.u);
      ast8(bb + (size_t)(mf * 2 + 1) * 512 + lane2 * 8 + i0, hl.u);
      __syncthreads();
    };
    if (DO1) epi(acc1, bs1, c1, h1w);
    if (DO0) epi(acc0, bs0, c0, h0w);
  };

  // ---------- head GEMM: group-local, 16 of 32 WGs, 32 rows x 64 cols ----------
  // yp != null: head1 (pack y1). yp == null: head2 + fused fc3 (atomicAdd to out).
  auto headg = [&](const us* apack, const us* Wp, const float* bias,
                   us* yp, int kidx) {
    if (lb < 16) {
      const int mhl = lb >> 3, cb = lb & 7;
      const int hrow0 = row0 + mhl * 32, hj0 = cb * 64;
      const int wm = w >> 1, wn = w & 1;
      f32x4 hacc[2];
      hacc[0] = {0.f, 0.f, 0.f, 0.f};
      hacc[1] = {0.f, 0.f, 0.f, 0.f};
      HSetA HA0, HA1, HA2, HA3;
      HSetB HB0, HB1;
      auto hissA = [&](int c, HSetA& R) {
        if (c >= 16) return;
        const us* a = apack + (size_t)(m * 16 + c) * 4096 + mhl * 2048;
        R.a0 = ald8(a + tid * 8);
        R.a1 = ald8(a + tid * 8 + 4);
      };
      auto hissB = [&](int c, HSetB& R) {
        if (c >= 16) return;
        const us* b = Wp + (size_t)(cb * 16 + c) * 4096 + wn * 2048 + l * 8;
        R.b0h = *(const s16x8*)(b);
        R.b0l = *(const s16x8*)(b + 512);
        R.b1h = *(const s16x8*)(b + 1024);
        R.b1l = *(const s16x8*)(b + 1536);
      };
      auto hwrtA = [&](int c, HSetA& R) {
        if (c >= 16) return;
        int sl = c % 3;
        *(ull*)&Ash[sl][tid * 8] = R.a0;
        *(ull*)&Ash[sl][tid * 8 + 4] = R.a1;
      };
      auto hcmp = [&](int sl, HSetB& B) {
        s16x8 Ah = *(const s16x8*)&Ash[sl][(wm * 2 + 0) * 512 + l * 8];
        s16x8 Al = *(const s16x8*)&Ash[sl][(wm * 2 + 1) * 512 + l * 8];
        hacc[0] = __builtin_amdgcn_mfma_f32_16x16x32_bf16(Ah, B.b0h, hacc[0], 0, 0, 0);
        hacc[0] = __builtin_amdgcn_mfma_f32_16x16x32_bf16(Ah, B.b0l, hacc[0], 0, 0, 0);
        hacc[0] = __builtin_amdgcn_mfma_f32_16x16x32_bf16(Al, B.b0h, hacc[0], 0, 0, 0);
        hacc[1] = __builtin_amdgcn_mfma_f32_16x16x32_bf16(Ah, B.b1h, hacc[1], 0, 0, 0);
        hacc[1] = __builtin_amdgcn_mfma_f32_16x16x32_bf16(Ah, B.b1l, hacc[1], 0, 0, 0);
        hacc[1] = __builtin_amdgcn_mfma_f32_16x16x32_bf16(Al, B.b1h, hacc[1], 0, 0, 0);
      };
      hissA(0, HA0); hissA(1, HA1); hissA(2, HA2); hissA(3, HA3);
      hwrtA(0, HA0); hissA(4, HA0);
      hwrtA(1, HA1); hissA(5, HA1);
      hissB(0, HB0); hissB(1, HB1);
      __syncthreads();
      for (int base = 0; base < 16; base += 4) {
        { int kc = base + 0; hcmp(kc % 3, HB0); hissB(kc + 2, HB0);
          hwrtA(kc + 2, HA2); hissA(kc + 6, HA2); __syncthreads(); }
        { int kc = base + 1; hcmp(kc % 3, HB1); hissB(kc + 2, HB1);
          hwrtA(kc + 2, HA3); hissA(kc + 6, HA3); __syncthreads(); }
        { int kc = base + 2; hcmp(kc % 3, HB0); hissB(kc + 2, HB0);
          hwrtA(kc + 2, HA0); hissA(kc + 6, HA0); __syncthreads(); }
        { int kc = base + 3; hcmp(kc % 3, HB1); hissB(kc + 2, HB1);
          hwrtA(kc + 2, HA1); hissA(kc + 6, HA1); __syncthreads(); }
      }
      __syncthreads();
      float* GsF = (float*)Gs;
      #pragma unroll
      for (int nf = 0; nf < 2; ++nf)
        #pragma unroll
        for (int rq = 0; rq < 4; ++rq) {
          int rr = wm * 16 + (l >> 4) * 4 + rq;
          int ccl = wn * 32 + nf * 16 + (l & 15);
          GsF[rr * 64 + ccl] = geluf(hacc[nf][rq] + bias[hj0 + ccl]);
        }
      __syncthreads();
      if (yp) {
        int chunk = tid >> 7, tt = tid & 127;
        int mf_loc = tt >> 6, lane = tt & 63;
        int row = mf_loc * 16 + (lane & 15);
        int kg = lane >> 4;
        S8 hi, lo;
        #pragma unroll
        for (int i = 0; i < 8; ++i) {
          float v = GsF[row * 64 + chunk * 32 + kg * 8 + i];
          us hh = f2bf(v);
          hi.v[i] = (short)hh;
          lo.v[i] = (short)f2bf(v - bf2f(hh));
        }
        us* dst = yp + ((size_t)m * 16 + (cb * 2 + chunk)) * 4096 + mhl * 2048;
        ast8(dst + (size_t)(mf_loc * 2 + 0) * 512 + lane * 8, hi.u[0]);
        ast8(dst + (size_t)(mf_loc * 2 + 0) * 512 + lane * 8 + 4, hi.u[1]);
        ast8(dst + (size_t)(mf_loc * 2 + 1) * 512 + lane * 8, lo.u[0]);
        ast8(dst + (size_t)(mf_loc * 2 + 1) * 512 + lane * 8 + 4, lo.u[1]);
      } else {
        int r = tid >> 3, cg = tid & 7;
        float p0 = 0.f, p1 = 0.f;
        #pragma unroll
        for (int i = 0; i < 8; ++i) {
          float yv = GsF[r * 64 + cg * 8 + i];
          int col = hj0 + cg * 8 + i;
          p0 += yv * fc3_w[col];
          p1 += yv * fc3_w[512 + col];
        }
        #pragma unroll
        for (int d = 4; d > 0; d >>= 1) {
          p0 += __shfl_down(p0, d, 8);
          p1 += __shfl_down(p1, d, 8);
        }
        if (cg == 0) {
          atomicAdd(out + (size_t)(hrow0 + r) * OSTR + kidx * 2, p0);
          atomicAdd(out + (size_t)(hrow0 + r) * OSTR + kidx * 2 + 1, p1);
        }
      }
      __syncthreads();
    }
  };

  auto h1buf = [&](int t) { return (t & 1) ? hp1_1 : hp1_0; };

  // ================= schedule (8 independent groups) =================
  fused(false, true, 0, false, 0, true); garrive();          // t=0 (pre-safe)
  for (int t = 1; t < 64; ++t) { fused(true, true, t, false, 0, false); garrive(); }
  fused(true, false, 64, false, 0, false); garrive();        // L1(63), no pre

  for (int kidx = 0; kidx < 17; ++kidx) {
    const us* h1cur = h1buf(63 + kidx);
    gwait();
    headg(h1cur, Wpf1, fc1_b, y1p, kidx);
    if (lb == 16 && tid < 128) {
      int r2 = tid >> 1, o = tid & 1;
      ast4f(out + (size_t)(row0 + r2) * OSTR + kidx * 2 + o, fc3_b[o]);
    }
    garrive();
    gwait();
    headg(y1p, Wpf2, fc2_b, nullptr, kidx);
    garrive();
    if (kidx < 16) {
      fused(false, true, 64 + kidx, true, kidx, true); garrive();   // L0: pre h-chunks
      fused(true, false, 65 + kidx, false, 0, true); garrive();     // L1: pre 16..31
    }
  }
}

} // namespace

extern "C" void kernel_launch(void* const* d_in, const int* in_sizes, int n_in,
                              void* d_out, int out_size, void* d_ws, size_t ws_size,
                              hipStream_t stream) {
  const float* x     = (const float*)d_in[0];
  const float* w_ih0 = (const float*)d_in[1];
  const float* w_hh0 = (const float*)d_in[2];
  const float* b_ih0 = (const float*)d_in[3];
  const float* b_hh0 = (const float*)d_in[4];
  const float* w_ih1 = (const float*)d_in[5];
  const float* w_hh1 = (const float*)d_in[6];
  const float* b_ih1 = (const float*)d_in[7];
  const float* b_hh1 = (const float*)d_in[8];
  const float* fc1_w = (const float*)d_in[9];
  const float* fc1_b = (const float*)d_in[10];
  const float* fc2_w = (const float*)d_in[11];
  const float* fc2_b = (const float*)d_in[12];
  const float* fc3_w = (const float*)d_in[13];
  const float* fc3_b = (const float*)d_in[14];
  float* out = (float*)d_out;
  char* wsb = (char*)d_ws;

  constexpr size_t MB = 1048576;
  constexpr size_t O_WP0  = 0;
  constexpr size_t O_WP1  = 4456448;
  constexpr size_t O_WPF1 = O_WP1 + 8388608;
  constexpr size_t O_WPF2 = O_WPF1 + MB;
  constexpr size_t O_BS0  = O_WPF2 + MB;
  constexpr size_t O_BS1  = O_BS0 + 8192;
  constexpr size_t O_CNT  = O_BS1 + 8192;           // flags: 16 KB
  constexpr size_t O_HP0B = O_CNT + 16384;          // hp0_1 (zeroed)
  constexpr size_t O_HP1B = O_HP0B + MB;            // hp1_1 (zeroed)
  constexpr size_t O_C0   = O_HP1B + MB;            // c0 (zeroed)
  constexpr size_t O_C1   = O_C0 + MB;              // c1 (zeroed)
  constexpr size_t O_HP0A = O_C1 + MB;
  constexpr size_t O_HP1A = O_HP0A + MB;
  constexpr size_t O_Y1P  = O_HP1A + MB;

  us* Wp0  = (us*)(wsb + O_WP0);
  us* Wp1  = (us*)(wsb + O_WP1);
  us* Wpf1 = (us*)(wsb + O_WPF1);
  us* Wpf2 = (us*)(wsb + O_WPF2);
  float* bs0 = (float*)(wsb + O_BS0);
  float* bs1 = (float*)(wsb + O_BS1);
  int* cnt   = (int*)(wsb + O_CNT);
  us* hp0_1 = (us*)(wsb + O_HP0B);
  us* hp1_1 = (us*)(wsb + O_HP1B);
  float* c0 = (float*)(wsb + O_C0);
  float* c1 = (float*)(wsb + O_C1);
  us* hp0_0 = (us*)(wsb + O_HP0A);
  us* hp1_0 = (us*)(wsb + O_HP1A);
  us* y1p   = (us*)(wsb + O_Y1P);

  pack_w_kernel<<<dim3(32 * 17), 256, 0, stream>>>(w_ih0, w_hh0, 32, 512, 17, 0, Wp0);
  pack_w_kernel<<<dim3(32 * 32), 256, 0, stream>>>(w_ih1, w_hh1, 512, 512, 32, 0, Wp1);
  pack_w_kernel<<<dim3(8 * 16), 256, 0, stream>>>(fc1_w, fc1_w, 512, 512, 16, 1, Wpf1);
  pack_w_kernel<<<dim3(8 * 16), 256, 0, stream>>>(fc2_w, fc2_w, 512, 512, 16, 1, Wpf2);
  bsum_kernel<<<dim3(16), 256, 0, stream>>>(b_ih0, b_hh0, b_ih1, b_hh1, bs0, bs1);
  // zero: flags (16KB) + hp0_1,hp1_1,c0,c1 (4MB) — contiguous
  hipMemsetAsync(wsb + O_CNT, 0, 16384 + 4 * MB, stream);

  persist_kernel<<<dim3(256), dim3(256), 0, stream>>>(
      x, Wp0, Wp1, Wpf1, Wpf2, bs0, bs1, fc1_b, fc2_b, fc3_w, fc3_b,
      hp0_0, hp0_1, hp1_0, hp1_1, c0, c1, y1p, out, cnt);
}

// Round 18
// 1522.428 us; speedup vs baseline: 1.9404x; 1.5618x over previous
//
#include <hip/hip_runtime.h>
#include <math.h>

typedef short s16x4 __attribute__((ext_vector_type(4)));
typedef short s16x8 __attribute__((ext_vector_type(8)));
typedef float f32x4 __attribute__((ext_vector_type(4)));
typedef unsigned short us;
typedef unsigned long long ull;

#define WAITVM(N) do { asm volatile("s_waitcnt vmcnt(" #N ")" ::: "memory"); __builtin_amdgcn_sched_barrier(0); } while (0)

namespace {
constexpr int T = 80, Fdim = 32, H = 512, OSTR = 34;
constexpr int CH = 2048;   // us elements per 64-row / per-weight chunk (fp16 single)

__device__ __forceinline__ us f2h(float f) {
  union { _Float16 h; us u; } x; x.h = (_Float16)f; return x.u;
}
__device__ __forceinline__ float sigf(float v) { return 1.f / (1.f + expf(-v)); }
__device__ __forceinline__ float geluf(float v) {
  return 0.5f * v * (1.f + erff(v * 0.70710678118654752f));
}

__device__ __forceinline__ ull ald8(const void* p) {
  return __hip_atomic_load((const ull*)p, __ATOMIC_RELAXED, __HIP_MEMORY_SCOPE_AGENT);
}
__device__ __forceinline__ void ast8(void* p, ull v) {
  __hip_atomic_store((ull*)p, v, __ATOMIC_RELAXED, __HIP_MEMORY_SCOPE_AGENT);
}
__device__ __forceinline__ void ast4f(float* p, float v) {
  __hip_atomic_store(p, v, __ATOMIC_RELAXED, __HIP_MEMORY_SCOPE_AGENT);
}

union U8 { ull u; s16x4 v4; float f[2]; };
union S8 { s16x8 v; ull u[2]; };

struct SetA { ull a0, a1; };
struct SetB { s16x8 b1, b0; };
struct HSetA { ull a0; };
struct HSetB { s16x8 b0, b1; };

// ---------------- weight pre-pack: single fp16, fragment-linear ----------------
// chunk (4KB) idx = jb*NKC + kc: [strip(4)][lane(64)][8 fp16]
__global__ __launch_bounds__(256)
void pack_w_kernel(const float* __restrict__ w1, const float* __restrict__ w2,
                   int K1, int K2, int NKC, int head, us* __restrict__ dst) {
  int bid = blockIdx.x;
  int jb = bid / NKC, kc = bid % NKC;
  int tid = threadIdx.x;
  int strip = tid >> 6, l = tid & 63;
  int nl = l & 15, kg = l >> 4;
  int n = head ? (jb * 64 + strip * 16 + nl) : (strip * 512 + jb * 16 + nl);
  s16x8 h8;
  #pragma unroll
  for (int i = 0; i < 8; ++i) {
    int k = kc * 32 + kg * 8 + i;
    float v = (k < K1) ? w1[(size_t)n * K1 + k] : w2[(size_t)n * K2 + (k - K1)];
    h8[i] = (short)f2h(v);
  }
  *(s16x8*)&dst[(size_t)bid * CH + strip * 512 + l * 8] = h8;
}

__global__ __launch_bounds__(256)
void bsum_kernel(const float* bi0, const float* bh0, const float* bi1, const float* bh1,
                 float* bs0, float* bs1) {
  int i = blockIdx.x * 256 + threadIdx.x;
  if (i < 2048) bs0[i] = bi0[i] + bh0[i];
  else { int j = i - 2048; bs1[j] = bi1[j] + bh1[j]; }
}

// ---------------- persistent whole-model kernel ----------------
// 256 WGs = 8 groups (64 rows) x 32 WGs (16 h-cols). Single-fp16 datapath.
__global__ __launch_bounds__(256, 1)
void persist_kernel(const float* __restrict__ x,
                    const us* __restrict__ Wp0, const us* __restrict__ Wp1,
                    const us* __restrict__ Wpf1, const us* __restrict__ Wpf2,
                    const float* __restrict__ bs0, const float* __restrict__ bs1,
                    const float* __restrict__ fc1_b, const float* __restrict__ fc2_b,
                    const float* __restrict__ fc3_w, const float* __restrict__ fc3_b,
                    us* hp0_0, us* hp0_1, us* hp1_0, us* hp1_1,
                    float* c0, float* c1, us* y1p,
                    float* out, int* cnt)
{
  __shared__ __align__(16) us Ash[8][2048];
  __shared__ __align__(16) float Gs[4][64][16];

  const int tid = threadIdx.x;
  const int bid = blockIdx.x;
  const int w = tid >> 6, l = tid & 63;
  const int m = bid >> 5;                      // group 0..7 (64 rows)
  const int lb = bid & 31;                     // group-local WG id
  const int jb = (lb & 7) * 4 + (lb >> 3);     // h-col slice 0..31
  const int row0 = m * 64;
  const int j0 = jb * 16;
  const int base31 = j0 & 31;

  const us* WpJ0 = Wp0 + (size_t)jb * 17 * CH;
  const us* WpJ1 = Wp1 + (size_t)jb * 32 * CH;

  int ph = 0;
  auto garrive = [&]() {
    ++ph;
    WAITVM(0);
    __syncthreads();
    if (tid == 0)
      __hip_atomic_store(&cnt[m * 512 + lb * 16], ph, __ATOMIC_RELEASE,
                         __HIP_MEMORY_SCOPE_AGENT);
  };
  auto gwait = [&]() {
    if (tid < 32) {
      while (__hip_atomic_load(&cnt[m * 512 + tid * 16], __ATOMIC_RELAXED,
                               __HIP_MEMORY_SCOPE_AGENT) < ph)
        __builtin_amdgcn_s_sleep(1);
      __builtin_amdgcn_fence(__ATOMIC_ACQUIRE, "workgroup");
    }
    __syncthreads();
  };

  // ---------- fused LSTM phase: {L1(t-1) if DO1} + {L0(t) if DO0} ----------
  auto fused = [&](bool DO1, bool DO0, int t, bool use_fb, int kidx, bool preh) {
    const us* h0prev = ((t + 1) & 1) ? hp0_1 : hp0_0;
    const us* h1prev = (t & 1) ? hp1_1 : hp1_0;
    us* h1w = ((t + 1) & 1) ? hp1_1 : hp1_0;
    us* h0w = (t & 1) ? hp0_1 : hp0_0;

    f32x4 acc0[4], acc1[4];
    #pragma unroll
    for (int mf = 0; mf < 4; ++mf) {
      acc0[mf] = {0.f, 0.f, 0.f, 0.f};
      acc1[mf] = {0.f, 0.f, 0.f, 0.f};
    }
    const int NP = DO1 ? 32 : 16;
    SetA A0s, A1s, A2s, A3s;
    SetB B0s, B1s, B2s, B3s;

    auto issA = [&](int c, SetA& R, int hi) {
      if (c >= hi) return;
      const us* a = ((c < 16) ? h0prev : h1prev) + (size_t)(m * 16 + (c & 15)) * CH;
      R.a0 = ald8(a + tid * 8);
      R.a1 = ald8(a + tid * 8 + 4);
    };
    auto issB = [&](int c, SetB& R, int hi) {
      if (c >= hi) return;
      if (DO1) R.b1 = *(const s16x8*)(WpJ1 + (size_t)c * CH + w * 512 + l * 8);
      if (DO0 && c < 16)
        R.b0 = *(const s16x8*)(WpJ0 + (size_t)(c + 1) * CH + w * 512 + l * 8);
    };
    auto wrtA = [&](int c, SetA& R, int hi) {
      if (c >= hi) return;
      int sl = c & 7;
      *(ull*)&Ash[sl][tid * 8] = R.a0;
      *(ull*)&Ash[sl][tid * 8 + 4] = R.a1;
    };
    auto lcomp = [&](int kc, SetB& B, bool c1on, bool c0on) {
      int sl = kc & 7;
      #pragma unroll
      for (int mf = 0; mf < 4; ++mf) {
        s16x8 Ah = *(const s16x8*)&Ash[sl][mf * 512 + l * 8];
        if (c1on)
          acc1[mf] = __builtin_amdgcn_mfma_f32_16x16x32_f16(Ah, B.b1, acc1[mf], 0, 0, 0);
        if (c0on)
          acc0[mf] = __builtin_amdgcn_mfma_f32_16x16x32_f16(Ah, B.b0, acc0[mf], 0, 0, 0);
      }
    };

    auto runseg = [&](int lo, int hi) {
      issA(lo + 0, A0s, hi); issA(lo + 1, A1s, hi);
      issA(lo + 2, A2s, hi); issA(lo + 3, A3s, hi);
      wrtA(lo + 0, A0s, hi); wrtA(lo + 1, A1s, hi);
      wrtA(lo + 2, A2s, hi); wrtA(lo + 3, A3s, hi);
      issA(lo + 4, A0s, hi); issA(lo + 5, A1s, hi);
      issA(lo + 6, A2s, hi); issA(lo + 7, A3s, hi);
      __syncthreads();
      for (int base = lo; base < hi; base += 4) {
        { int kc = base + 0; lcomp(kc, B0s, DO1, DO0 && kc < 16); issB(kc + 4, B0s, hi); }
        { int kc = base + 1; lcomp(kc, B1s, DO1, DO0 && kc < 16); issB(kc + 4, B1s, hi); }
        { int kc = base + 2; lcomp(kc, B2s, DO1, DO0 && kc < 16); issB(kc + 4, B2s, hi); }
        { int kc = base + 3; lcomp(kc, B3s, DO1, DO0 && kc < 16); issB(kc + 4, B3s, hi); }
        __syncthreads();
        wrtA(base + 4, A0s, hi); wrtA(base + 5, A1s, hi);
        wrtA(base + 6, A2s, hi); wrtA(base + 7, A3s, hi);
        issA(base + 8, A0s, hi); issA(base + 9, A1s, hi);
        issA(base + 10, A2s, hi); issA(base + 11, A3s, hi);
        __syncthreads();
      }
    };

    if (preh) {
      if (DO1) {
        issB(16, B0s, 32); issB(17, B1s, 32); issB(18, B2s, 32); issB(19, B3s, 32);
        runseg(16, 32);
        issB(0, B0s, 16); issB(1, B1s, 16); issB(2, B2s, 16); issB(3, B3s, 16);
        gwait();
        runseg(0, 16);
      } else {
        issB(0, B0s, 16); issB(1, B1s, 16); issB(2, B2s, 16); issB(3, B3s, 16);
        runseg(0, 16);
        gwait();
      }
    } else {
      issB(0, B0s, NP); issB(1, B1s, NP); issB(2, B2s, NP); issB(3, B3s, NP);
      gwait();
      runseg(0, NP);
    }

    if (DO0) {  // x chunk (L0 weight chunk 0) — post-barrier (feedback)
      SetB Bx;
      Bx.b0 = *(const s16x8*)(WpJ0 + w * 512 + l * 8);
      int srow = tid >> 2, skg = tid & 3;
      const float* xp = x + (size_t)(row0 + srow) * (T * Fdim) + (size_t)t * Fdim + skg * 8;
      float v[8];
      #pragma unroll
      for (int i = 0; i < 8; ++i) v[i] = xp[i];
      if (use_fb && skg == 0) {
        const float* op = out + (size_t)(row0 + srow) * OSTR + kidx * 2;
        v[4] = __hip_atomic_load(op, __ATOMIC_RELAXED, __HIP_MEMORY_SCOPE_AGENT);
        v[5] = __hip_atomic_load(op + 1, __ATOMIC_RELAXED, __HIP_MEMORY_SCOPE_AGENT);
      }
      s16x8 h8;
      #pragma unroll
      for (int i = 0; i < 8; ++i) h8[i] = (short)f2h(v[i]);
      int slane = skg * 16 + (srow & 15), smf = srow >> 4;
      *(s16x8*)&Ash[0][smf * 512 + slane * 8] = h8;
      __syncthreads();
      lcomp(0, Bx, false, true);
    }

    // epilogue: stash gates -> cell -> packed coherent h write (fp16)
    auto epi = [&](f32x4* acc, const float* bsum, float* cst, us* hw) {
      __syncthreads();
      float bsv = bsum[w * 512 + j0 + (l & 15)];
      #pragma unroll
      for (int mf = 0; mf < 4; ++mf)
        #pragma unroll
        for (int r = 0; r < 4; ++r)
          Gs[w][mf * 16 + (l >> 4) * 4 + r][l & 15] = acc[mf][r] + bsv;
      __syncthreads();
      int r = tid >> 2, sub = tid & 3, cc0 = sub * 4;
      float gvi[4], gvf[4], gvg[4], gvo[4], cv[4], cn[4], hv[4];
      #pragma unroll
      for (int q = 0; q < 4; ++q) {
        gvi[q] = Gs[0][r][cc0 + q]; gvf[q] = Gs[1][r][cc0 + q];
        gvg[q] = Gs[2][r][cc0 + q]; gvo[q] = Gs[3][r][cc0 + q];
      }
      size_t cix = (size_t)(row0 + r) * H + j0 + cc0;
      float4 cold = *(const float4*)&cst[cix];
      cv[0] = cold.x; cv[1] = cold.y; cv[2] = cold.z; cv[3] = cold.w;
      #pragma unroll
      for (int q = 0; q < 4; ++q) {
        float c2 = sigf(gvf[q]) * cv[q] + sigf(gvi[q]) * tanhf(gvg[q]);
        cn[q] = c2;
        hv[q] = sigf(gvo[q]) * tanhf(c2);
      }
      *(float4*)&cst[cix] = make_float4(cn[0], cn[1], cn[2], cn[3]);
      int kk = base31 + cc0;
      int kg = kk >> 3, i0 = kk & 7;
      int mf = r >> 4;
      int lane2 = kg * 16 + (r & 15);
      us* bb = hw + (size_t)(m * 16 + (j0 >> 5)) * CH;
      U8 hh;
      #pragma unroll
      for (int q = 0; q < 4; ++q) hh.v4[q] = (short)f2h(hv[q]);
      ast8(bb + (size_t)mf * 512 + lane2 * 8 + i0, hh.u);
      __syncthreads();
    };
    if (DO1) epi(acc1, bs1, c1, h1w);
    if (DO0) epi(acc0, bs0, c0, h0w);
  };

  // ---------- head GEMM: 16 of 32 WGs, 32 rows x 64 cols ----------
  auto headg = [&](const us* apack, const us* Wp, const float* bias,
                   us* yp, int kidx) {
    if (lb < 16) {
      const int mhl = lb >> 3, cb = lb & 7;
      const int hrow0 = row0 + mhl * 32, hj0 = cb * 64;
      const int wm = w >> 1, wn = w & 1;
      f32x4 hacc[2];
      hacc[0] = {0.f, 0.f, 0.f, 0.f};
      hacc[1] = {0.f, 0.f, 0.f, 0.f};
      HSetA HA0, HA1, HA2, HA3;
      HSetB HB0, HB1;
      auto hissA = [&](int c, HSetA& R) {
        if (c >= 16) return;
        const us* a = apack + (size_t)(m * 16 + c) * CH + mhl * 1024;
        R.a0 = ald8(a + tid * 4);
      };
      auto hissB = [&](int c, HSetB& R) {
        if (c >= 16) return;
        const us* b = Wp + (size_t)(cb * 16 + c) * CH + wn * 1024 + l * 8;
        R.b0 = *(const s16x8*)(b);
        R.b1 = *(const s16x8*)(b + 512);
      };
      auto hwrtA = [&](int c, HSetA& R) {
        if (c >= 16) return;
        int sl = c % 3;
        *(ull*)&Ash[sl][tid * 4] = R.a0;
      };
      auto hcmp = [&](int sl, HSetB& B) {
        s16x8 Ah = *(const s16x8*)&Ash[sl][wm * 512 + l * 8];
        hacc[0] = __builtin_amdgcn_mfma_f32_16x16x32_f16(Ah, B.b0, hacc[0], 0, 0, 0);
        hacc[1] = __builtin_amdgcn_mfma_f32_16x16x32_f16(Ah, B.b1, hacc[1], 0, 0, 0);
      };
      hissA(0, HA0); hissA(1, HA1); hissA(2, HA2); hissA(3, HA3);
      hwrtA(0, HA0); hissA(4, HA0);
      hwrtA(1, HA1); hissA(5, HA1);
      hissB(0, HB0); hissB(1, HB1);
      __syncthreads();
      for (int base = 0; base < 16; base += 4) {
        { int kc = base + 0; hcmp(kc % 3, HB0); hissB(kc + 2, HB0);
          hwrtA(kc + 2, HA2); hissA(kc + 6, HA2); __syncthreads(); }
        { int kc = base + 1; hcmp(kc % 3, HB1); hissB(kc + 2, HB1);
          hwrtA(kc + 2, HA3); hissA(kc + 6, HA3); __syncthreads(); }
        { int kc = base + 2; hcmp(kc % 3, HB0); hissB(kc + 2, HB0);
          hwrtA(kc + 2, HA0); hissA(kc + 6, HA0); __syncthreads(); }
        { int kc = base + 3; hcmp(kc % 3, HB1); hissB(kc + 2, HB1);
          hwrtA(kc + 2, HA1); hissA(kc + 6, HA1); __syncthreads(); }
      }
      __syncthreads();
      float* GsF = (float*)Gs;
      #pragma unroll
      for (int nf = 0; nf < 2; ++nf)
        #pragma unroll
        for (int rq = 0; rq < 4; ++rq) {
          int rr = wm * 16 + (l >> 4) * 4 + rq;
          int ccl = wn * 32 + nf * 16 + (l & 15);
          GsF[rr * 64 + ccl] = geluf(hacc[nf][rq] + bias[hj0 + ccl]);
        }
      __syncthreads();
      if (yp) {
        // head1: pack fp16 fragment layout (consumable as head2 A)
        int chunk = tid >> 7, tt = tid & 127;
        int mf_loc = tt >> 6, lane = tt & 63;
        int row = mf_loc * 16 + (lane & 15);
        int kg = lane >> 4;
        S8 hv;
        #pragma unroll
        for (int i = 0; i < 8; ++i)
          hv.v[i] = (short)f2h(GsF[row * 64 + chunk * 32 + kg * 8 + i]);
        us* dst = yp + ((size_t)m * 16 + (cb * 2 + chunk)) * CH;
        ast8(dst + (size_t)(mhl * 2 + mf_loc) * 512 + lane * 8, hv.u[0]);
        ast8(dst + (size_t)(mhl * 2 + mf_loc) * 512 + lane * 8 + 4, hv.u[1]);
      } else {
        // head2 + fc3: partial dot over this WG's 64 cols, atomicAdd into out
        int r = tid >> 3, cg = tid & 7;
        float p0 = 0.f, p1 = 0.f;
        #pragma unroll
        for (int i = 0; i < 8; ++i) {
          float yv = GsF[r * 64 + cg * 8 + i];
          int col = hj0 + cg * 8 + i;
          p0 += yv * fc3_w[col];
          p1 += yv * fc3_w[512 + col];
        }
        #pragma unroll
        for (int d = 4; d > 0; d >>= 1) {
          p0 += __shfl_down(p0, d, 8);
          p1 += __shfl_down(p1, d, 8);
        }
        if (cg == 0) {
          atomicAdd(out + (size_t)(hrow0 + r) * OSTR + kidx * 2, p0);
          atomicAdd(out + (size_t)(hrow0 + r) * OSTR + kidx * 2 + 1, p1);
        }
      }
      __syncthreads();
    }
  };

  auto h1buf = [&](int t) { return (t & 1) ? hp1_1 : hp1_0; };

  // ================= schedule (8 independent groups) =================
  fused(false, true, 0, false, 0, true); garrive();          // t=0 (pre-safe)
  for (int t = 1; t < 64; ++t) { fused(true, true, t, false, 0, false); garrive(); }
  fused(true, false, 64, false, 0, false); garrive();        // L1(63)

  for (int kidx = 0; kidx < 17; ++kidx) {
    const us* h1cur = h1buf(63 + kidx);
    gwait();
    headg(h1cur, Wpf1, fc1_b, y1p, kidx);
    if (lb == 16 && tid < 128) {
      int r2 = tid >> 1, o = tid & 1;
      ast4f(out + (size_t)(row0 + r2) * OSTR + kidx * 2 + o, fc3_b[o]);
    }
    garrive();
    gwait();
    headg(y1p, Wpf2, fc2_b, nullptr, kidx);
    garrive();
    if (kidx < 16) {
      fused(false, true, 64 + kidx, true, kidx, true); garrive();
      fused(true, false, 65 + kidx, false, 0, true); garrive();
    }
  }
}

} // namespace

extern "C" void kernel_launch(void* const* d_in, const int* in_sizes, int n_in,
                              void* d_out, int out_size, void* d_ws, size_t ws_size,
                              hipStream_t stream) {
  const float* x     = (const float*)d_in[0];
  const float* w_ih0 = (const float*)d_in[1];
  const float* w_hh0 = (const float*)d_in[2];
  const float* b_ih0 = (const float*)d_in[3];
  const float* b_hh0 = (const float*)d_in[4];
  const float* w_ih1 = (const float*)d_in[5];
  const float* w_hh1 = (const float*)d_in[6];
  const float* b_ih1 = (const float*)d_in[7];
  const float* b_hh1 = (const float*)d_in[8];
  const float* fc1_w = (const float*)d_in[9];
  const float* fc1_b = (const float*)d_in[10];
  const float* fc2_w = (const float*)d_in[11];
  const float* fc2_b = (const float*)d_in[12];
  const float* fc3_w = (const float*)d_in[13];
  const float* fc3_b = (const float*)d_in[14];
  float* out = (float*)d_out;
  char* wsb = (char*)d_ws;

  constexpr size_t KB = 1024;
  constexpr size_t O_WP0  = 0;                          // 32*17*4KB = 2228224
  constexpr size_t O_WP1  = 2228224;                    // 32*32*4KB = 4194304
  constexpr size_t O_WPF1 = O_WP1 + 4194304;            // 8*16*4KB = 524288
  constexpr size_t O_WPF2 = O_WPF1 + 524288;
  constexpr size_t O_BS0  = O_WPF2 + 524288;            // 8192
  constexpr size_t O_BS1  = O_BS0 + 8192;
  constexpr size_t O_CNT  = O_BS1 + 8192;               // flags 16 KB
  constexpr size_t O_HP0B = O_CNT + 16384;              // hp0_1 (zeroed, 512K)
  constexpr size_t O_HP1B = O_HP0B + 512 * KB;          // hp1_1 (zeroed, 512K)
  constexpr size_t O_C0   = O_HP1B + 512 * KB;          // c0 (zeroed, 1M)
  constexpr size_t O_C1   = O_C0 + 1024 * KB;           // c1 (zeroed, 1M)
  constexpr size_t O_HP0A = O_C1 + 1024 * KB;
  constexpr size_t O_HP1A = O_HP0A + 512 * KB;
  constexpr size_t O_Y1P  = O_HP1A + 512 * KB;

  us* Wp0  = (us*)(wsb + O_WP0);
  us* Wp1  = (us*)(wsb + O_WP1);
  us* Wpf1 = (us*)(wsb + O_WPF1);
  us* Wpf2 = (us*)(wsb + O_WPF2);
  float* bs0 = (float*)(wsb + O_BS0);
  float* bs1 = (float*)(wsb + O_BS1);
  int* cnt   = (int*)(wsb + O_CNT);
  us* hp0_1 = (us*)(wsb + O_HP0B);
  us* hp1_1 = (us*)(wsb + O_HP1B);
  float* c0 = (float*)(wsb + O_C0);
  float* c1 = (float*)(wsb + O_C1);
  us* hp0_0 = (us*)(wsb + O_HP0A);
  us* hp1_0 = (us*)(wsb + O_HP1A);
  us* y1p   = (us*)(wsb + O_Y1P);

  pack_w_kernel<<<dim3(32 * 17), 256, 0, stream>>>(w_ih0, w_hh0, 32, 512, 17, 0, Wp0);
  pack_w_kernel<<<dim3(32 * 32), 256, 0, stream>>>(w_ih1, w_hh1, 512, 512, 32, 0, Wp1);
  pack_w_kernel<<<dim3(8 * 16), 256, 0, stream>>>(fc1_w, fc1_w, 512, 512, 16, 1, Wpf1);
  pack_w_kernel<<<dim3(8 * 16), 256, 0, stream>>>(fc2_w, fc2_w, 512, 512, 16, 1, Wpf2);
  bsum_kernel<<<dim3(16), 256, 0, stream>>>(b_ih0, b_hh0, b_ih1, b_hh1, bs0, bs1);
  // zero: flags (16KB) + hp0_1, hp1_1 (1MB) + c0, c1 (2MB) — contiguous
  hipMemsetAsync(wsb + O_CNT, 0, 16384 + 3 * 1024 * KB, stream);

  persist_kernel<<<dim3(256), dim3(256), 0, stream>>>(
      x, Wp0, Wp1, Wpf1, Wpf2, bs0, bs1, fc1_b, fc2_b, fc3_w, fc3_b,
      hp0_0, hp0_1, hp1_0, hp1_1, c0, c1, y1p, out, cnt);
}